// Round 6
// baseline (303.109 us; speedup 1.0000x reference)
//
#include <hip/hip_runtime.h>
#include <hip/hip_bf16.h>

typedef __attribute__((ext_vector_type(8))) short short8;
typedef __attribute__((ext_vector_type(4))) float floatx4;

#define D 128

__device__ __forceinline__ unsigned short f2bf(float f) {
    unsigned u = __float_as_uint(f);
    u += 0x7FFFu + ((u >> 16) & 1u);   // round-to-nearest-even
    return (unsigned short)(u >> 16);
}
__device__ __forceinline__ float bf2f(unsigned short h) {
    return __uint_as_float(((unsigned)h) << 16);
}
__device__ __forceinline__ float bflo(unsigned p) { return __uint_as_float(p << 16); }
__device__ __forceinline__ float bfhi(unsigned p) { return __uint_as_float(p & 0xFFFF0000u); }

// Lock-free per-dst linked list: head[d] -> newest edge, next[e] -> older edge.
// next[] store is COALESCED (edge order); only the 4B atomicExch is random
// (200 KB array, memory-side op). Replaces count+scan+CSR-scatter fill.
__global__ void link_kernel(const int* __restrict__ dst, int* __restrict__ head,
                            int* __restrict__ next, int E) {
    int t4 = (blockIdx.x * blockDim.x + threadIdx.x) * 4;
    if (t4 + 3 < E) {
        int4 d = *reinterpret_cast<const int4*>(dst + t4);
        int o0 = atomicExch(&head[d.x], t4);
        int o1 = atomicExch(&head[d.y], t4 + 1);
        int o2 = atomicExch(&head[d.z], t4 + 2);
        int o3 = atomicExch(&head[d.w], t4 + 3);
        *reinterpret_cast<int4*>(next + t4) = make_int4(o0, o1, o2, o3);
    } else {
        for (int i = t4; i < E; i++) next[i] = atomicExch(&head[dst[i]], i);
    }
}

// One thread per node: chain length = in-degree; dinv = rsqrt(deg+1).
__global__ __launch_bounds__(256) void degdinv_kernel(const int* __restrict__ head,
                                                      const int* __restrict__ next,
                                                      float* __restrict__ dinv, int N) {
    int i = blockIdx.x * blockDim.x + threadIdx.x;
    if (i >= N) return;
    int c = 0;
    int e = head[i];
    while (e >= 0) { c++; e = next[e]; }
    dinv[i] = rsqrtf((float)(c + 1));
}

// spack[e] = (src[e], dinv[src[e]]) — coalesced write, random L2 gather of dinv.
__global__ void spack_kernel(const int* __restrict__ src, const float* __restrict__ dinv,
                             int2* __restrict__ spack, int E) {
    int t4 = (blockIdx.x * blockDim.x + threadIdx.x) * 4;
    if (t4 + 3 < E) {
        int4 s = *reinterpret_cast<const int4*>(src + t4);
        float c0 = dinv[s.x], c1 = dinv[s.y], c2 = dinv[s.z], c3 = dinv[s.w];
        spack[t4]     = make_int2(s.x, __float_as_int(c0));
        spack[t4 + 1] = make_int2(s.y, __float_as_int(c1));
        spack[t4 + 2] = make_int2(s.z, __float_as_int(c2));
        spack[t4 + 3] = make_int2(s.w, __float_as_int(c3));
    } else {
        for (int i = t4; i < E; i++) {
            int s = src[i];
            spack[i] = make_int2(s, __float_as_int(dinv[s]));
        }
    }
}

// Convert BOTH weight matrices (fp32 128x128 [k][n]) into hi/lo bf16 MFMA
// B-fragment layout: out[((kb*4+quad)*128 + col)*8 + j] = W[(kb*32+quad*8+j)*128+col]
__global__ __launch_bounds__(256) void wconv_kernel(const float* __restrict__ W1,
                                                    const float* __restrict__ W2,
                                                    unsigned short* __restrict__ whi1,
                                                    unsigned short* __restrict__ wlo1,
                                                    unsigned short* __restrict__ whi2,
                                                    unsigned short* __restrict__ wlo2) {
    int gid = blockIdx.x * 256 + threadIdx.x;      // 0..32767
    int which = gid >> 14;
    int tid = gid & 16383;
    const float* W = which ? W2 : W1;
    unsigned short* whi = which ? whi2 : whi1;
    unsigned short* wlo = which ? wlo2 : wlo1;
    int j    = tid & 7;
    int col  = (tid >> 3) & 127;
    int quad = (tid >> 10) & 3;
    int kb   = tid >> 12;
    float wv = W[(kb * 32 + quad * 8 + j) * D + col];
    unsigned u = __float_as_uint(wv);
    unsigned short h = (unsigned short)(u >> 16);          // truncate for hi
    whi[tid] = h;
    wlo[tid] = f2bf(wv - bf2f(h));
}

// Layer-1 GEMM: C[M,128](bf16) = A[M,128](fp32) @ W (pre-split hi/lo bf16).
// hi*hi + hi*lo + lo*hi fp32-MFMA accumulate -> ~2^-17 rel, then bf16 round.
__global__ __launch_bounds__(256) void gemm_f32a_kernel(const float* __restrict__ A,
                                                        const unsigned short* __restrict__ whi,
                                                        const unsigned short* __restrict__ wlo,
                                                        unsigned short* __restrict__ C, int M) {
    int lane = threadIdx.x & 63, wid = threadIdx.x >> 6;
    int quad = lane >> 4, l15 = lane & 15;
    int row0 = blockIdx.x * 64;
    int n0 = wid * 32;

    short8 bhi[2][4], blo[2][4];
    #pragma unroll
    for (int t = 0; t < 2; t++)
        #pragma unroll
        for (int kb = 0; kb < 4; kb++) {
            size_t base = ((size_t)((kb * 4 + quad) * 128 + (n0 + t * 16 + l15))) * 8;
            bhi[t][kb] = *reinterpret_cast<const short8*>(whi + base);
            blo[t][kb] = *reinterpret_cast<const short8*>(wlo + base);
        }

    #pragma unroll
    for (int rg = 0; rg < 4; rg++) {
        int r0 = row0 + rg * 16;
        int ar = r0 + l15; if (ar > M - 1) ar = M - 1;
        short8 ahi[4], alo[4];
        #pragma unroll
        for (int kb = 0; kb < 4; kb++) {
            const float4* ap = reinterpret_cast<const float4*>(A + (size_t)ar * D + kb * 32 + quad * 8);
            float4 v0 = ap[0], v1 = ap[1];
            float vv[8] = {v0.x, v0.y, v0.z, v0.w, v1.x, v1.y, v1.z, v1.w};
            short8 vh, vl;
            #pragma unroll
            for (int j = 0; j < 8; j++) {
                unsigned u = __float_as_uint(vv[j]);
                unsigned short h = (unsigned short)(u >> 16);
                vh[j] = (short)h;
                vl[j] = (short)f2bf(vv[j] - bf2f(h));
            }
            ahi[kb] = vh;
            alo[kb] = vl;
        }
        floatx4 acc0 = {0.f, 0.f, 0.f, 0.f};
        floatx4 acc1 = {0.f, 0.f, 0.f, 0.f};
        #pragma unroll
        for (int kb = 0; kb < 4; kb++) {
            acc0 = __builtin_amdgcn_mfma_f32_16x16x32_bf16(ahi[kb], bhi[0][kb], acc0, 0, 0, 0);
            acc1 = __builtin_amdgcn_mfma_f32_16x16x32_bf16(ahi[kb], bhi[1][kb], acc1, 0, 0, 0);
            acc0 = __builtin_amdgcn_mfma_f32_16x16x32_bf16(ahi[kb], blo[0][kb], acc0, 0, 0, 0);
            acc1 = __builtin_amdgcn_mfma_f32_16x16x32_bf16(ahi[kb], blo[1][kb], acc1, 0, 0, 0);
            acc0 = __builtin_amdgcn_mfma_f32_16x16x32_bf16(alo[kb], bhi[0][kb], acc0, 0, 0, 0);
            acc1 = __builtin_amdgcn_mfma_f32_16x16x32_bf16(alo[kb], bhi[1][kb], acc1, 0, 0, 0);
        }
        #pragma unroll
        for (int r = 0; r < 4; r++) {
            int orow = r0 + quad * 4 + r;
            if (orow < M) {
                C[(size_t)orow * D + n0 + l15]      = f2bf(acc0[r]);
                C[(size_t)orow * D + n0 + 16 + l15] = f2bf(acc1[r]);
            }
        }
    }
}

// Layer-2 GEMM: A is already bf16 -> exact; 4 MFMAs/kb, direct short8 loads.
__global__ __launch_bounds__(256) void gemm_bf16a_kernel(const unsigned short* __restrict__ A,
                                                         const unsigned short* __restrict__ whi,
                                                         const unsigned short* __restrict__ wlo,
                                                         unsigned short* __restrict__ C, int M) {
    int lane = threadIdx.x & 63, wid = threadIdx.x >> 6;
    int quad = lane >> 4, l15 = lane & 15;
    int row0 = blockIdx.x * 64;
    int n0 = wid * 32;

    short8 bhi[2][4], blo[2][4];
    #pragma unroll
    for (int t = 0; t < 2; t++)
        #pragma unroll
        for (int kb = 0; kb < 4; kb++) {
            size_t base = ((size_t)((kb * 4 + quad) * 128 + (n0 + t * 16 + l15))) * 8;
            bhi[t][kb] = *reinterpret_cast<const short8*>(whi + base);
            blo[t][kb] = *reinterpret_cast<const short8*>(wlo + base);
        }

    #pragma unroll
    for (int rg = 0; rg < 4; rg++) {
        int r0 = row0 + rg * 16;
        int ar = r0 + l15; if (ar > M - 1) ar = M - 1;
        short8 af[4];
        #pragma unroll
        for (int kb = 0; kb < 4; kb++)
            af[kb] = *reinterpret_cast<const short8*>(A + (size_t)ar * D + kb * 32 + quad * 8);
        floatx4 acc0 = {0.f, 0.f, 0.f, 0.f};
        floatx4 acc1 = {0.f, 0.f, 0.f, 0.f};
        #pragma unroll
        for (int kb = 0; kb < 4; kb++) {
            acc0 = __builtin_amdgcn_mfma_f32_16x16x32_bf16(af[kb], bhi[0][kb], acc0, 0, 0, 0);
            acc1 = __builtin_amdgcn_mfma_f32_16x16x32_bf16(af[kb], bhi[1][kb], acc1, 0, 0, 0);
            acc0 = __builtin_amdgcn_mfma_f32_16x16x32_bf16(af[kb], blo[0][kb], acc0, 0, 0, 0);
            acc1 = __builtin_amdgcn_mfma_f32_16x16x32_bf16(af[kb], blo[1][kb], acc1, 0, 0, 0);
        }
        #pragma unroll
        for (int r = 0; r < 4; r++) {
            int orow = r0 + quad * 4 + r;
            if (orow < M) {
                C[(size_t)orow * D + n0 + l15]      = f2bf(acc0[r]);
                C[(size_t)orow * D + n0 + 16 + l15] = f2bf(acc1[r]);
            }
        }
    }
}

// Shared agg body: wave walks node's edge chain in chunks of 8 (serial
// wave-uniform next-hops), then issues the 8 feature gathers in parallel.
__device__ __forceinline__ float2 agg_body(const unsigned* __restrict__ H32,
                                           const float* __restrict__ dinv,
                                           const int* __restrict__ head,
                                           const int* __restrict__ next,
                                           const int2* __restrict__ spack,
                                           const float* __restrict__ bias,
                                           int node, int lane) {
    float ax = 0.f, ay = 0.f;
    int e = head[node];
    while (e >= 0) {
        int ids[8];
        int n = 0;
        while (n < 8 && e >= 0) { ids[n++] = e; e = next[e]; }
        int2 q[8];
        #pragma unroll
        for (int i = 0; i < 8; i++) if (i < n) q[i] = spack[ids[i]];
        unsigned p[8];
        #pragma unroll
        for (int i = 0; i < 8; i++) if (i < n) p[i] = H32[(size_t)q[i].x * 64 + lane];
        #pragma unroll
        for (int i = 0; i < 8; i++)
            if (i < n) {
                float c = __int_as_float(q[i].y);
                ax += c * bflo(p[i]);
                ay += c * bfhi(p[i]);
            }
    }
    float di = dinv[node];
    unsigned ps = H32[(size_t)node * 64 + lane];
    float2 bb = ((const float2*)bias)[lane];
    float2 r;
    r.x = di * ax + di * di * bflo(ps) + bb.x;
    r.y = di * ay + di * di * bfhi(ps) + bb.y;
    return r;
}

// Layer-1 agg: + ReLU, packed bf16 output.
__global__ __launch_bounds__(256) void agg_bf16out_kernel(const unsigned short* __restrict__ H,
                                                          const float* __restrict__ dinv,
                                                          const int* __restrict__ head,
                                                          const int* __restrict__ next,
                                                          const int2* __restrict__ spack,
                                                          const float* __restrict__ bias,
                                                          unsigned* __restrict__ out, int N) {
    int node = (int)((blockIdx.x * (unsigned)blockDim.x + threadIdx.x) >> 6);
    int lane = threadIdx.x & 63;
    if (node >= N) return;
    float2 r = agg_body((const unsigned*)H, dinv, head, next, spack, bias, node, lane);
    r.x = fmaxf(r.x, 0.f);
    r.y = fmaxf(r.y, 0.f);
    out[(size_t)node * 64 + lane] = (unsigned)f2bf(r.x) | ((unsigned)f2bf(r.y) << 16);
}

// Layer-2 agg: fp32 output to d_out.
__global__ __launch_bounds__(256) void agg_f32out_kernel(const unsigned short* __restrict__ H,
                                                         const float* __restrict__ dinv,
                                                         const int* __restrict__ head,
                                                         const int* __restrict__ next,
                                                         const int2* __restrict__ spack,
                                                         const float* __restrict__ bias,
                                                         float2* __restrict__ out, int N) {
    int node = (int)((blockIdx.x * (unsigned)blockDim.x + threadIdx.x) >> 6);
    int lane = threadIdx.x & 63;
    if (node >= N) return;
    float2 r = agg_body((const unsigned*)H, dinv, head, next, spack, bias, node, lane);
    out[(size_t)node * 64 + lane] = r;
}

extern "C" void kernel_launch(void* const* d_in, const int* in_sizes, int n_in,
                              void* d_out, int out_size, void* d_ws, size_t ws_size,
                              hipStream_t stream) {
    const float* x  = (const float*)d_in[0];
    const int*   ei = (const int*)d_in[1];
    const float* W1 = (const float*)d_in[2];
    const float* b1 = (const float*)d_in[3];
    const float* W2 = (const float*)d_in[4];
    const float* b2 = (const float*)d_in[5];

    int N = in_sizes[0] / D;       // 50000
    int E = in_sizes[1] / 2;       // 600000
    const int* src = ei;
    const int* dst = ei + E;

    char* ws = (char*)d_ws;
    int*   head = (int*)(ws + 0);                  // N ints
    int*   next = (int*)(ws + 200064);             // E ints -> 2600064
    float* dinv = (float*)(ws + 2600064);          // N floats -> 2800064 (pad 2800128)
    int2*  spack = (int2*)(ws + 2800128);          // E int2 (4.8 MB) -> 7600128
    unsigned short* whi1 = (unsigned short*)(ws + 7600128);  // 16384 bf16
    unsigned short* wlo1 = (unsigned short*)(ws + 7632896);
    unsigned short* whi2 = (unsigned short*)(ws + 7665664);
    unsigned short* wlo2 = (unsigned short*)(ws + 7698432);
    unsigned short* hfeat = (unsigned short*)(ws + 7731200);  // N*D bf16 (12.8 MB)
    unsigned short* hmid  = (unsigned short*)(ws + 20531200); // N*D bf16 (12.8 MB)
    float2* outp = (float2*)d_out;

    int nb  = (N + 255) / 256;       // node-parallel blocks
    int eb4 = (E / 4 + 255) / 256;   // 4-edge-per-thread blocks
    int gb  = (N + 63) / 64;         // gemm blocks
    int ab  = (N + 3) / 4;           // agg blocks (4 nodes/block)

    hipMemsetAsync(head, 0xFF, (size_t)N * sizeof(int), stream);   // head = -1
    link_kernel<<<eb4, 256, 0, stream>>>(dst, head, next, E);
    degdinv_kernel<<<nb, 256, 0, stream>>>(head, next, dinv, N);
    spack_kernel<<<eb4, 256, 0, stream>>>(src, dinv, spack, E);
    wconv_kernel<<<128, 256, 0, stream>>>(W1, W2, whi1, wlo1, whi2, wlo2);

    // layer 1: h1 = x @ W1 (bf16) ; agg + b1 + relu -> hmid (bf16)
    gemm_f32a_kernel<<<gb, 256, 0, stream>>>(x, whi1, wlo1, hfeat, N);
    agg_bf16out_kernel<<<ab, 256, 0, stream>>>(hfeat, dinv, head, next, spack, b1, (unsigned*)hmid, N);

    // layer 2: h2 = hmid @ W2 (bf16) ; agg + b2 -> d_out (fp32)
    gemm_bf16a_kernel<<<gb, 256, 0, stream>>>(hmid, whi2, wlo2, hfeat, N);
    agg_f32out_kernel<<<ab, 256, 0, stream>>>(hfeat, dinv, head, next, spack, b2, outp, N);
}

// Round 7
// 301.028 us; speedup vs baseline: 1.0069x; 1.0069x over previous
//
#include <hip/hip_runtime.h>
#include <hip/hip_bf16.h>

typedef __attribute__((ext_vector_type(8))) short short8;
typedef __attribute__((ext_vector_type(4))) float floatx4;

#define D 128
#define BCAP 2048   // per-(bucket,sub) capacity; mean fill 383, +85 sigma safe

__device__ __forceinline__ unsigned short f2bf(float f) {
    unsigned u = __float_as_uint(f);
    u += 0x7FFFu + ((u >> 16) & 1u);   // round-to-nearest-even
    return (unsigned short)(u >> 16);
}
__device__ __forceinline__ float bf2f(unsigned short h) {
    return __uint_as_float(((unsigned)h) << 16);
}
__device__ __forceinline__ float bflo(unsigned p) { return __uint_as_float(p << 16); }
__device__ __forceinline__ float bfhi(unsigned p) { return __uint_as_float(p & 0xFFFF0000u); }

// Pass A: bin edges by dst>>8 into 196 buckets x 8 sub-lists (sub = blockIdx&7
// ~ XCD id so same-line appends come from one XCD -> full-line writebacks).
// Entry = (dst&255)<<16 | src  (4B; requires N <= 65536).
__global__ void bucket_kernel(const int* __restrict__ src, const int* __restrict__ dst,
                              int* __restrict__ bcnt, unsigned* __restrict__ bucket, int E) {
    int sub = blockIdx.x & 7;
    int t4 = (blockIdx.x * blockDim.x + threadIdx.x) * 4;
    if (t4 + 3 < E) {
        int4 s = *reinterpret_cast<const int4*>(src + t4);
        int4 d = *reinterpret_cast<const int4*>(dst + t4);
        #pragma unroll
        for (int k = 0; k < 4; k++) {
            int dd = (k == 0) ? d.x : (k == 1) ? d.y : (k == 2) ? d.z : d.w;
            int ss = (k == 0) ? s.x : (k == 1) ? s.y : (k == 2) ? s.z : s.w;
            int slot = ((dd >> 8) << 3) | sub;
            int pos = atomicAdd(&bcnt[slot], 1);
            if (pos < BCAP)
                bucket[((size_t)slot << 11) + pos] = ((unsigned)(dd & 255) << 16) | (unsigned)ss;
        }
    } else {
        for (int i = t4; i < E; i++) {
            int dd = dst[i], ss = src[i];
            int slot = ((dd >> 8) << 3) | sub;
            int pos = atomicAdd(&bcnt[slot], 1);
            if (pos < BCAP)
                bucket[((size_t)slot << 11) + pos] = ((unsigned)(dd & 255) << 16) | (unsigned)ss;
        }
    }
}

__device__ __forceinline__ int block_excl_scan256(int v, int* lds, int tid) {
    int lane = tid & 63, wid = tid >> 6;
    int x = v;
    #pragma unroll
    for (int d = 1; d < 64; d <<= 1) {
        int y = __shfl_up(x, d, 64);
        if (lane >= d) x += y;
    }
    if (lane == 63) lds[wid] = x;
    __syncthreads();
    if (tid == 0) {
        int run = 0;
        #pragma unroll
        for (int i = 0; i < 4; i++) { int t2 = lds[i]; lds[i] = run; run += t2; }
    }
    __syncthreads();
    return lds[wid] + x - v;   // exclusive prefix within block
}

// Pass B: one block per bucket. In-block: bucket-base scan (redundant across
// blocks, saves a dispatch), LDS histogram -> row_ptr/dinv, LDS-offset scatter
// of sorted src into an L2-local 12KB window.
__global__ __launch_bounds__(256) void build_kernel(const unsigned* __restrict__ bucket,
                                                    const int* __restrict__ bcnt,
                                                    int* __restrict__ row_ptr,
                                                    float* __restrict__ dinv,
                                                    int* __restrict__ esrc, int N, int E) {
    __shared__ int lds4[4];
    __shared__ int sbase[256];
    __shared__ int hist[256];
    __shared__ int cur[256];
    int tid = threadIdx.x;
    int b = blockIdx.x;
    int nbuk = gridDim.x;
    int tot = 0;
    if (tid < nbuk) {
        #pragma unroll
        for (int s = 0; s < 8; s++) tot += bcnt[tid * 8 + s];
    }
    int ex = block_excl_scan256(tot, lds4, tid);
    sbase[tid] = ex;
    hist[tid] = 0;
    __syncthreads();
    int base = sbase[b];
    // histogram over local dst
    for (int sub = 0; sub < 8; sub++) {
        int cnt = min(bcnt[b * 8 + sub], BCAP);
        const unsigned* bp = bucket + ((size_t)(b * 8 + sub) << 11);
        for (int i = tid; i < cnt; i += 256)
            atomicAdd(&hist[bp[i] >> 16], 1);
    }
    __syncthreads();
    int h = hist[tid];
    int off = block_excl_scan256(h, lds4, tid);
    cur[tid] = base + off;
    int node = b * 256 + tid;
    if (node < N) {
        row_ptr[node] = base + off;
        dinv[node] = rsqrtf((float)(h + 1));
    }
    if (b == 0 && tid == 0) row_ptr[N] = E;
    __syncthreads();
    // scatter into [base, base+tot) — hot L2 window, full-line writebacks
    for (int sub = 0; sub < 8; sub++) {
        int cnt = min(bcnt[b * 8 + sub], BCAP);
        const unsigned* bp = bucket + ((size_t)(b * 8 + sub) << 11);
        for (int i = tid; i < cnt; i += 256) {
            unsigned v = bp[i];
            int p = atomicAdd(&cur[v >> 16], 1);
            esrc[p] = (int)(v & 0xFFFFu);
        }
    }
}

// epack[p] = (src, dinv[src]) — coalesced read/write, random L2 gather of dinv.
__global__ void epack_kernel(const int* __restrict__ esrc, const float* __restrict__ dinv,
                             int2* __restrict__ epack, int E) {
    int t4 = (blockIdx.x * blockDim.x + threadIdx.x) * 4;
    if (t4 + 3 < E) {
        int4 s = *reinterpret_cast<const int4*>(esrc + t4);
        float c0 = dinv[s.x], c1 = dinv[s.y], c2 = dinv[s.z], c3 = dinv[s.w];
        epack[t4]     = make_int2(s.x, __float_as_int(c0));
        epack[t4 + 1] = make_int2(s.y, __float_as_int(c1));
        epack[t4 + 2] = make_int2(s.z, __float_as_int(c2));
        epack[t4 + 3] = make_int2(s.w, __float_as_int(c3));
    } else {
        for (int i = t4; i < E; i++) {
            int s = esrc[i];
            epack[i] = make_int2(s, __float_as_int(dinv[s]));
        }
    }
}

// Convert BOTH weight matrices (fp32 128x128 [k][n]) into hi/lo bf16 MFMA
// B-fragment layout: out[((kb*4+quad)*128 + col)*8 + j] = W[(kb*32+quad*8+j)*128+col]
__global__ __launch_bounds__(256) void wconv_kernel(const float* __restrict__ W1,
                                                    const float* __restrict__ W2,
                                                    unsigned short* __restrict__ whi1,
                                                    unsigned short* __restrict__ wlo1,
                                                    unsigned short* __restrict__ whi2,
                                                    unsigned short* __restrict__ wlo2) {
    int gid = blockIdx.x * 256 + threadIdx.x;      // 0..32767
    int which = gid >> 14;
    int tid = gid & 16383;
    const float* W = which ? W2 : W1;
    unsigned short* whi = which ? whi2 : whi1;
    unsigned short* wlo = which ? wlo2 : wlo1;
    int j    = tid & 7;
    int col  = (tid >> 3) & 127;
    int quad = (tid >> 10) & 3;
    int kb   = tid >> 12;
    float wv = W[(kb * 32 + quad * 8 + j) * D + col];
    unsigned u = __float_as_uint(wv);
    unsigned short h = (unsigned short)(u >> 16);          // truncate for hi
    whi[tid] = h;
    wlo[tid] = f2bf(wv - bf2f(h));
}

// Layer-1 GEMM: C[M,128](bf16) = A[M,128](fp32) @ W (pre-split hi/lo bf16).
__global__ __launch_bounds__(256) void gemm_f32a_kernel(const float* __restrict__ A,
                                                        const unsigned short* __restrict__ whi,
                                                        const unsigned short* __restrict__ wlo,
                                                        unsigned short* __restrict__ C, int M) {
    int lane = threadIdx.x & 63, wid = threadIdx.x >> 6;
    int quad = lane >> 4, l15 = lane & 15;
    int row0 = blockIdx.x * 64;
    int n0 = wid * 32;

    short8 bhi[2][4], blo[2][4];
    #pragma unroll
    for (int t = 0; t < 2; t++)
        #pragma unroll
        for (int kb = 0; kb < 4; kb++) {
            size_t base = ((size_t)((kb * 4 + quad) * 128 + (n0 + t * 16 + l15))) * 8;
            bhi[t][kb] = *reinterpret_cast<const short8*>(whi + base);
            blo[t][kb] = *reinterpret_cast<const short8*>(wlo + base);
        }

    #pragma unroll
    for (int rg = 0; rg < 4; rg++) {
        int r0 = row0 + rg * 16;
        int ar = r0 + l15; if (ar > M - 1) ar = M - 1;
        short8 ahi[4], alo[4];
        #pragma unroll
        for (int kb = 0; kb < 4; kb++) {
            const float4* ap = reinterpret_cast<const float4*>(A + (size_t)ar * D + kb * 32 + quad * 8);
            float4 v0 = ap[0], v1 = ap[1];
            float vv[8] = {v0.x, v0.y, v0.z, v0.w, v1.x, v1.y, v1.z, v1.w};
            short8 vh, vl;
            #pragma unroll
            for (int j = 0; j < 8; j++) {
                unsigned u = __float_as_uint(vv[j]);
                unsigned short h = (unsigned short)(u >> 16);
                vh[j] = (short)h;
                vl[j] = (short)f2bf(vv[j] - bf2f(h));
            }
            ahi[kb] = vh;
            alo[kb] = vl;
        }
        floatx4 acc0 = {0.f, 0.f, 0.f, 0.f};
        floatx4 acc1 = {0.f, 0.f, 0.f, 0.f};
        #pragma unroll
        for (int kb = 0; kb < 4; kb++) {
            acc0 = __builtin_amdgcn_mfma_f32_16x16x32_bf16(ahi[kb], bhi[0][kb], acc0, 0, 0, 0);
            acc1 = __builtin_amdgcn_mfma_f32_16x16x32_bf16(ahi[kb], bhi[1][kb], acc1, 0, 0, 0);
            acc0 = __builtin_amdgcn_mfma_f32_16x16x32_bf16(ahi[kb], blo[0][kb], acc0, 0, 0, 0);
            acc1 = __builtin_amdgcn_mfma_f32_16x16x32_bf16(ahi[kb], blo[1][kb], acc1, 0, 0, 0);
            acc0 = __builtin_amdgcn_mfma_f32_16x16x32_bf16(alo[kb], bhi[0][kb], acc0, 0, 0, 0);
            acc1 = __builtin_amdgcn_mfma_f32_16x16x32_bf16(alo[kb], bhi[1][kb], acc1, 0, 0, 0);
        }
        #pragma unroll
        for (int r = 0; r < 4; r++) {
            int orow = r0 + quad * 4 + r;
            if (orow < M) {
                C[(size_t)orow * D + n0 + l15]      = f2bf(acc0[r]);
                C[(size_t)orow * D + n0 + 16 + l15] = f2bf(acc1[r]);
            }
        }
    }
}

// Layer-2 GEMM: A already bf16 -> exact; direct short8 loads.
__global__ __launch_bounds__(256) void gemm_bf16a_kernel(const unsigned short* __restrict__ A,
                                                         const unsigned short* __restrict__ whi,
                                                         const unsigned short* __restrict__ wlo,
                                                         unsigned short* __restrict__ C, int M) {
    int lane = threadIdx.x & 63, wid = threadIdx.x >> 6;
    int quad = lane >> 4, l15 = lane & 15;
    int row0 = blockIdx.x * 64;
    int n0 = wid * 32;

    short8 bhi[2][4], blo[2][4];
    #pragma unroll
    for (int t = 0; t < 2; t++)
        #pragma unroll
        for (int kb = 0; kb < 4; kb++) {
            size_t base = ((size_t)((kb * 4 + quad) * 128 + (n0 + t * 16 + l15))) * 8;
            bhi[t][kb] = *reinterpret_cast<const short8*>(whi + base);
            blo[t][kb] = *reinterpret_cast<const short8*>(wlo + base);
        }

    #pragma unroll
    for (int rg = 0; rg < 4; rg++) {
        int r0 = row0 + rg * 16;
        int ar = r0 + l15; if (ar > M - 1) ar = M - 1;
        short8 af[4];
        #pragma unroll
        for (int kb = 0; kb < 4; kb++)
            af[kb] = *reinterpret_cast<const short8*>(A + (size_t)ar * D + kb * 32 + quad * 8);
        floatx4 acc0 = {0.f, 0.f, 0.f, 0.f};
        floatx4 acc1 = {0.f, 0.f, 0.f, 0.f};
        #pragma unroll
        for (int kb = 0; kb < 4; kb++) {
            acc0 = __builtin_amdgcn_mfma_f32_16x16x32_bf16(af[kb], bhi[0][kb], acc0, 0, 0, 0);
            acc1 = __builtin_amdgcn_mfma_f32_16x16x32_bf16(af[kb], bhi[1][kb], acc1, 0, 0, 0);
            acc0 = __builtin_amdgcn_mfma_f32_16x16x32_bf16(af[kb], blo[0][kb], acc0, 0, 0, 0);
            acc1 = __builtin_amdgcn_mfma_f32_16x16x32_bf16(af[kb], blo[1][kb], acc1, 0, 0, 0);
        }
        #pragma unroll
        for (int r = 0; r < 4; r++) {
            int orow = r0 + quad * 4 + r;
            if (orow < M) {
                C[(size_t)orow * D + n0 + l15]      = f2bf(acc0[r]);
                C[(size_t)orow * D + n0 + 16 + l15] = f2bf(acc1[r]);
            }
        }
    }
}

// CSR agg body (round-5 structure): 8/4/1-edge unrolled gather loops.
__device__ __forceinline__ float2 agg_body(const unsigned* __restrict__ H32,
                                           const float* __restrict__ dinv,
                                           const int* __restrict__ row_ptr,
                                           const int2* __restrict__ epack,
                                           const float* __restrict__ bias,
                                           int node, int lane) {
    float ax = 0.f, ay = 0.f;
    int beg = row_ptr[node], end = row_ptr[node + 1];
    int e = beg;
    for (; e + 8 <= end; e += 8) {
        int2 q[8];
        #pragma unroll
        for (int i = 0; i < 8; i++) q[i] = epack[e + i];
        unsigned p[8];
        #pragma unroll
        for (int i = 0; i < 8; i++) p[i] = H32[(size_t)q[i].x * 64 + lane];
        #pragma unroll
        for (int i = 0; i < 8; i++) {
            float c = __int_as_float(q[i].y);
            ax += c * bflo(p[i]);
            ay += c * bfhi(p[i]);
        }
    }
    for (; e + 4 <= end; e += 4) {
        int2 q0 = epack[e], q1 = epack[e + 1], q2 = epack[e + 2], q3 = epack[e + 3];
        unsigned p0 = H32[(size_t)q0.x * 64 + lane];
        unsigned p1 = H32[(size_t)q1.x * 64 + lane];
        unsigned p2 = H32[(size_t)q2.x * 64 + lane];
        unsigned p3 = H32[(size_t)q3.x * 64 + lane];
        float c0 = __int_as_float(q0.y), c1 = __int_as_float(q1.y);
        float c2 = __int_as_float(q2.y), c3 = __int_as_float(q3.y);
        ax += c0 * bflo(p0) + c1 * bflo(p1) + c2 * bflo(p2) + c3 * bflo(p3);
        ay += c0 * bfhi(p0) + c1 * bfhi(p1) + c2 * bfhi(p2) + c3 * bfhi(p3);
    }
    for (; e < end; e++) {
        int2 q0 = epack[e];
        unsigned p0 = H32[(size_t)q0.x * 64 + lane];
        float c0 = __int_as_float(q0.y);
        ax += c0 * bflo(p0);
        ay += c0 * bfhi(p0);
    }
    float di = dinv[node];
    unsigned ps = H32[(size_t)node * 64 + lane];
    float2 bb = ((const float2*)bias)[lane];
    float2 r;
    r.x = di * ax + di * di * bflo(ps) + bb.x;
    r.y = di * ay + di * di * bfhi(ps) + bb.y;
    return r;
}

// Layer-1 agg: + ReLU, packed bf16 output.
__global__ __launch_bounds__(256) void agg_bf16out_kernel(const unsigned short* __restrict__ H,
                                                          const float* __restrict__ dinv,
                                                          const int* __restrict__ row_ptr,
                                                          const int2* __restrict__ epack,
                                                          const float* __restrict__ bias,
                                                          unsigned* __restrict__ out, int N) {
    int node = (int)((blockIdx.x * (unsigned)blockDim.x + threadIdx.x) >> 6);
    int lane = threadIdx.x & 63;
    if (node >= N) return;
    float2 r = agg_body((const unsigned*)H, dinv, row_ptr, epack, bias, node, lane);
    r.x = fmaxf(r.x, 0.f);
    r.y = fmaxf(r.y, 0.f);
    out[(size_t)node * 64 + lane] = (unsigned)f2bf(r.x) | ((unsigned)f2bf(r.y) << 16);
}

// Layer-2 agg: fp32 output to d_out.
__global__ __launch_bounds__(256) void agg_f32out_kernel(const unsigned short* __restrict__ H,
                                                         const float* __restrict__ dinv,
                                                         const int* __restrict__ row_ptr,
                                                         const int2* __restrict__ epack,
                                                         const float* __restrict__ bias,
                                                         float2* __restrict__ out, int N) {
    int node = (int)((blockIdx.x * (unsigned)blockDim.x + threadIdx.x) >> 6);
    int lane = threadIdx.x & 63;
    if (node >= N) return;
    float2 r = agg_body((const unsigned*)H, dinv, row_ptr, epack, bias, node, lane);
    out[(size_t)node * 64 + lane] = r;
}

extern "C" void kernel_launch(void* const* d_in, const int* in_sizes, int n_in,
                              void* d_out, int out_size, void* d_ws, size_t ws_size,
                              hipStream_t stream) {
    const float* x  = (const float*)d_in[0];
    const int*   ei = (const int*)d_in[1];
    const float* W1 = (const float*)d_in[2];
    const float* b1 = (const float*)d_in[3];
    const float* W2 = (const float*)d_in[4];
    const float* b2 = (const float*)d_in[5];

    int N = in_sizes[0] / D;       // 50000 (pack requires N <= 65536)
    int E = in_sizes[1] / 2;       // 600000
    const int* src = ei;
    const int* dst = ei + E;

    int nbuk = (N + 255) / 256;    // 196 buckets

    char* ws = (char*)d_ws;
    int*      bcnt   = (int*)(ws + 0);                    // nbuk*8 ints (6272 B)
    unsigned* bucket = (unsigned*)(ws + 6400);            // nbuk*8*BCAP*4 = 12.85 MB
    int*      row_ptr= (int*)(ws + 12851456);             // N+1 ints
    float*    dinv   = (float*)(ws + 13051520);           // N floats
    int*      esrcs  = (int*)(ws + 13251520);             // E ints (sorted by dst)
    int2*     epack  = (int2*)(ws + 15651584);            // E int2 (4.8 MB)
    unsigned short* whi1 = (unsigned short*)(ws + 20451584);
    unsigned short* wlo1 = (unsigned short*)(ws + 20484352);
    unsigned short* whi2 = (unsigned short*)(ws + 20517120);
    unsigned short* wlo2 = (unsigned short*)(ws + 20549888);
    unsigned short* hfeat = (unsigned short*)(ws + 20582656); // N*D bf16 (12.8 MB)
    unsigned short* hmid  = (unsigned short*)(ws + 33382656); // N*D bf16 (12.8 MB)
    float2* outp = (float2*)d_out;

    int eb4 = (E / 4 + 255) / 256;   // 4-edge-per-thread blocks (586)
    int gb  = (N + 63) / 64;         // gemm blocks
    int ab  = (N + 3) / 4;           // agg blocks (4 nodes/block)

    hipMemsetAsync(bcnt, 0, (size_t)nbuk * 8 * sizeof(int), stream);
    bucket_kernel<<<eb4, 256, 0, stream>>>(src, dst, bcnt, bucket, E);
    build_kernel<<<nbuk, 256, 0, stream>>>(bucket, bcnt, row_ptr, dinv, esrcs, N, E);
    epack_kernel<<<eb4, 256, 0, stream>>>(esrcs, dinv, epack, E);
    wconv_kernel<<<128, 256, 0, stream>>>(W1, W2, whi1, wlo1, whi2, wlo2);

    // layer 1: h1 = x @ W1 (bf16) ; agg + b1 + relu -> hmid (bf16)
    gemm_f32a_kernel<<<gb, 256, 0, stream>>>(x, whi1, wlo1, hfeat, N);
    agg_bf16out_kernel<<<ab, 256, 0, stream>>>(hfeat, dinv, row_ptr, epack, b1, (unsigned*)hmid, N);

    // layer 2: h2 = hmid @ W2 (bf16) ; agg + b2 -> d_out (fp32)
    gemm_bf16a_kernel<<<gb, 256, 0, stream>>>(hmid, whi2, wlo2, hfeat, N);
    agg_f32out_kernel<<<ab, 256, 0, stream>>>(hfeat, dinv, row_ptr, epack, b2, outp, N);
}

// Round 8
// 238.735 us; speedup vs baseline: 1.2696x; 1.2609x over previous
//
#include <hip/hip_runtime.h>
#include <hip/hip_bf16.h>

typedef __attribute__((ext_vector_type(8))) short short8;
typedef __attribute__((ext_vector_type(4))) float floatx4;

#define D 128

__device__ __forceinline__ unsigned short f2bf(float f) {
    unsigned u = __float_as_uint(f);
    u += 0x7FFFu + ((u >> 16) & 1u);   // round-to-nearest-even
    return (unsigned short)(u >> 16);
}
__device__ __forceinline__ float bf2f(unsigned short h) {
    return __uint_as_float(((unsigned)h) << 16);
}
__device__ __forceinline__ float bflo(unsigned p) { return __uint_as_float(p << 16); }
__device__ __forceinline__ float bfhi(unsigned p) { return __uint_as_float(p & 0xFFFF0000u); }

__device__ __forceinline__ int block_excl_scan256(int v, int* lds, int tid) {
    int lane = tid & 63, wid = tid >> 6;
    int x = v;
    #pragma unroll
    for (int d = 1; d < 64; d <<= 1) {
        int y = __shfl_up(x, d, 64);
        if (lane >= d) x += y;
    }
    if (lane == 63) lds[wid] = x;
    __syncthreads();
    if (tid == 0) {
        int run = 0;
        #pragma unroll
        for (int i = 0; i < 4; i++) { int t2 = lds[i]; lds[i] = run; run += t2; }
    }
    __syncthreads();
    return lds[wid] + x - v;   // exclusive prefix within block
}

// Fused: blocks [0,eb4) count in-degrees (4 edges/thread, random atomics over
// 50k counters = 3125 lines -> low line contention); blocks [eb4, eb4+128)
// convert both weight matrices to hi/lo bf16 MFMA B-fragment layout.
__global__ __launch_bounds__(256) void count_wconv_kernel(const int* __restrict__ dst,
                                                          int* __restrict__ cnt, int E,
                                                          const float* __restrict__ W1,
                                                          const float* __restrict__ W2,
                                                          unsigned short* __restrict__ whi1,
                                                          unsigned short* __restrict__ wlo1,
                                                          unsigned short* __restrict__ whi2,
                                                          unsigned short* __restrict__ wlo2,
                                                          int eb4) {
    int b = blockIdx.x;
    if (b >= eb4) {
        int gid = (b - eb4) * 256 + threadIdx.x;      // 0..32767
        int which = gid >> 14;
        int tid = gid & 16383;
        const float* W = which ? W2 : W1;
        unsigned short* whi = which ? whi2 : whi1;
        unsigned short* wlo = which ? wlo2 : wlo1;
        int j    = tid & 7;
        int col  = (tid >> 3) & 127;
        int quad = (tid >> 10) & 3;
        int kb   = tid >> 12;
        float wv = W[(kb * 32 + quad * 8 + j) * D + col];
        unsigned u = __float_as_uint(wv);
        unsigned short h = (unsigned short)(u >> 16);          // truncate for hi
        whi[tid] = h;
        wlo[tid] = f2bf(wv - bf2f(h));
        return;
    }
    int t4 = (b * 256 + threadIdx.x) * 4;
    if (t4 + 3 < E) {
        int4 d = *reinterpret_cast<const int4*>(dst + t4);
        atomicAdd(&cnt[d.x], 1);
        atomicAdd(&cnt[d.y], 1);
        atomicAdd(&cnt[d.z], 1);
        atomicAdd(&cnt[d.w], 1);
    } else {
        for (int i = t4; i < E; i++) atomicAdd(&cnt[dst[i]], 1);
    }
}

// phase 1: per-block sums of cnt
__global__ __launch_bounds__(256) void scan1_kernel(const int* __restrict__ cnt,
                                                    int* __restrict__ bsum, int N) {
    __shared__ int lds[4];
    int tid = threadIdx.x;
    int idx = blockIdx.x * 256 + tid;
    int v = (idx < N) ? cnt[idx] : 0;
    int lane = tid & 63, wid = tid >> 6;
    #pragma unroll
    for (int d = 32; d > 0; d >>= 1) v += __shfl_down(v, d, 64);
    if (lane == 0) lds[wid] = v;
    __syncthreads();
    if (tid == 0) bsum[blockIdx.x] = lds[0] + lds[1] + lds[2] + lds[3];
}

// phase 2 (fused): each block redundantly scans the <=256 block sums in-LDS,
// then applies its base to the per-node exclusive scan. Drops a dispatch.
__global__ __launch_bounds__(256) void scan3_kernel(const int* __restrict__ cnt,
                                                    const int* __restrict__ bsum,
                                                    int* __restrict__ row_ptr,
                                                    int* __restrict__ row_next,
                                                    float* __restrict__ dinv,
                                                    int N, int E, int nb) {
    __shared__ int lds4[4];
    __shared__ int sbase[256];
    int tid = threadIdx.x;
    int tot = (tid < nb) ? bsum[tid] : 0;
    int ex = block_excl_scan256(tot, lds4, tid);
    sbase[tid] = ex;
    __syncthreads();
    int base = sbase[blockIdx.x];
    int idx = blockIdx.x * 256 + tid;
    int v = (idx < N) ? cnt[idx] : 0;
    int e = base + block_excl_scan256(v, lds4, tid);
    if (idx < N) {
        row_ptr[idx]  = e;
        row_next[idx] = e;
        dinv[idx] = rsqrtf((float)(v + 1));
    }
    if (idx == 0) row_ptr[N] = E;
}

// Fused: blocks [0,eb4) do the CSR scatter fill (latency-bound, low occupancy);
// blocks [eb4, eb4+gb) do the layer-1 GEMM (MFMA-dense). Independent chains —
// co-residency hides fill's atomic/scatter latency under GEMM compute.
__global__ __launch_bounds__(256) void fill_gemm_kernel(const int* __restrict__ src,
                                                        const int* __restrict__ dst,
                                                        const float* __restrict__ dinv,
                                                        int* __restrict__ row_next,
                                                        int2* __restrict__ epack, int E,
                                                        const float* __restrict__ A,
                                                        const unsigned short* __restrict__ whi,
                                                        const unsigned short* __restrict__ wlo,
                                                        unsigned short* __restrict__ C, int M,
                                                        int eb4) {
    if (blockIdx.x < eb4) {
        int t4 = (blockIdx.x * 256 + threadIdx.x) * 4;
        if (t4 + 3 < E) {
            int4 s = *reinterpret_cast<const int4*>(src + t4);
            int4 d = *reinterpret_cast<const int4*>(dst + t4);
            float c0 = dinv[s.x], c1 = dinv[s.y], c2 = dinv[s.z], c3 = dinv[s.w];
            int p0 = atomicAdd(&row_next[d.x], 1);
            int p1 = atomicAdd(&row_next[d.y], 1);
            int p2 = atomicAdd(&row_next[d.z], 1);
            int p3 = atomicAdd(&row_next[d.w], 1);
            epack[p0] = make_int2(s.x, __float_as_int(c0));
            epack[p1] = make_int2(s.y, __float_as_int(c1));
            epack[p2] = make_int2(s.z, __float_as_int(c2));
            epack[p3] = make_int2(s.w, __float_as_int(c3));
        } else {
            for (int i = t4; i < E; i++) {
                int s = src[i];
                int p = atomicAdd(&row_next[dst[i]], 1);
                epack[p] = make_int2(s, __float_as_int(dinv[s]));
            }
        }
        return;
    }
    // ---- layer-1 GEMM: C[M,128](bf16) = A[M,128](fp32) @ W (hi/lo bf16 split)
    int lane = threadIdx.x & 63, wid = threadIdx.x >> 6;
    int quad = lane >> 4, l15 = lane & 15;
    int row0 = (blockIdx.x - eb4) * 64;
    int n0 = wid * 32;

    short8 bhi[2][4], blo[2][4];
    #pragma unroll
    for (int t = 0; t < 2; t++)
        #pragma unroll
        for (int kb = 0; kb < 4; kb++) {
            size_t base = ((size_t)((kb * 4 + quad) * 128 + (n0 + t * 16 + l15))) * 8;
            bhi[t][kb] = *reinterpret_cast<const short8*>(whi + base);
            blo[t][kb] = *reinterpret_cast<const short8*>(wlo + base);
        }

    #pragma unroll
    for (int rg = 0; rg < 4; rg++) {
        int r0 = row0 + rg * 16;
        int ar = r0 + l15; if (ar > M - 1) ar = M - 1;
        short8 ahi[4], alo[4];
        #pragma unroll
        for (int kb = 0; kb < 4; kb++) {
            const float4* ap = reinterpret_cast<const float4*>(A + (size_t)ar * D + kb * 32 + quad * 8);
            float4 v0 = ap[0], v1 = ap[1];
            float vv[8] = {v0.x, v0.y, v0.z, v0.w, v1.x, v1.y, v1.z, v1.w};
            short8 vh, vl;
            #pragma unroll
            for (int j = 0; j < 8; j++) {
                unsigned u = __float_as_uint(vv[j]);
                unsigned short h = (unsigned short)(u >> 16);
                vh[j] = (short)h;
                vl[j] = (short)f2bf(vv[j] - bf2f(h));
            }
            ahi[kb] = vh;
            alo[kb] = vl;
        }
        floatx4 acc0 = {0.f, 0.f, 0.f, 0.f};
        floatx4 acc1 = {0.f, 0.f, 0.f, 0.f};
        #pragma unroll
        for (int kb = 0; kb < 4; kb++) {
            acc0 = __builtin_amdgcn_mfma_f32_16x16x32_bf16(ahi[kb], bhi[0][kb], acc0, 0, 0, 0);
            acc1 = __builtin_amdgcn_mfma_f32_16x16x32_bf16(ahi[kb], bhi[1][kb], acc1, 0, 0, 0);
            acc0 = __builtin_amdgcn_mfma_f32_16x16x32_bf16(ahi[kb], blo[0][kb], acc0, 0, 0, 0);
            acc1 = __builtin_amdgcn_mfma_f32_16x16x32_bf16(ahi[kb], blo[1][kb], acc1, 0, 0, 0);
            acc0 = __builtin_amdgcn_mfma_f32_16x16x32_bf16(alo[kb], bhi[0][kb], acc0, 0, 0, 0);
            acc1 = __builtin_amdgcn_mfma_f32_16x16x32_bf16(alo[kb], bhi[1][kb], acc1, 0, 0, 0);
        }
        #pragma unroll
        for (int r = 0; r < 4; r++) {
            int orow = r0 + quad * 4 + r;
            if (orow < M) {
                C[(size_t)orow * D + n0 + l15]      = f2bf(acc0[r]);
                C[(size_t)orow * D + n0 + 16 + l15] = f2bf(acc1[r]);
            }
        }
    }
}

// Layer-2 GEMM: A already bf16 -> exact; direct short8 loads.
__global__ __launch_bounds__(256) void gemm_bf16a_kernel(const unsigned short* __restrict__ A,
                                                         const unsigned short* __restrict__ whi,
                                                         const unsigned short* __restrict__ wlo,
                                                         unsigned short* __restrict__ C, int M) {
    int lane = threadIdx.x & 63, wid = threadIdx.x >> 6;
    int quad = lane >> 4, l15 = lane & 15;
    int row0 = blockIdx.x * 64;
    int n0 = wid * 32;

    short8 bhi[2][4], blo[2][4];
    #pragma unroll
    for (int t = 0; t < 2; t++)
        #pragma unroll
        for (int kb = 0; kb < 4; kb++) {
            size_t base = ((size_t)((kb * 4 + quad) * 128 + (n0 + t * 16 + l15))) * 8;
            bhi[t][kb] = *reinterpret_cast<const short8*>(whi + base);
            blo[t][kb] = *reinterpret_cast<const short8*>(wlo + base);
        }

    #pragma unroll
    for (int rg = 0; rg < 4; rg++) {
        int r0 = row0 + rg * 16;
        int ar = r0 + l15; if (ar > M - 1) ar = M - 1;
        short8 af[4];
        #pragma unroll
        for (int kb = 0; kb < 4; kb++)
            af[kb] = *reinterpret_cast<const short8*>(A + (size_t)ar * D + kb * 32 + quad * 8);
        floatx4 acc0 = {0.f, 0.f, 0.f, 0.f};
        floatx4 acc1 = {0.f, 0.f, 0.f, 0.f};
        #pragma unroll
        for (int kb = 0; kb < 4; kb++) {
            acc0 = __builtin_amdgcn_mfma_f32_16x16x32_bf16(af[kb], bhi[0][kb], acc0, 0, 0, 0);
            acc1 = __builtin_amdgcn_mfma_f32_16x16x32_bf16(af[kb], bhi[1][kb], acc1, 0, 0, 0);
            acc0 = __builtin_amdgcn_mfma_f32_16x16x32_bf16(af[kb], blo[0][kb], acc0, 0, 0, 0);
            acc1 = __builtin_amdgcn_mfma_f32_16x16x32_bf16(af[kb], blo[1][kb], acc1, 0, 0, 0);
        }
        #pragma unroll
        for (int r = 0; r < 4; r++) {
            int orow = r0 + quad * 4 + r;
            if (orow < M) {
                C[(size_t)orow * D + n0 + l15]      = f2bf(acc0[r]);
                C[(size_t)orow * D + n0 + 16 + l15] = f2bf(acc1[r]);
            }
        }
    }
}

// CSR agg body: 8/4/1-edge unrolled gather loops.
__device__ __forceinline__ float2 agg_body(const unsigned* __restrict__ H32,
                                           const float* __restrict__ dinv,
                                           const int* __restrict__ row_ptr,
                                           const int2* __restrict__ epack,
                                           const float* __restrict__ bias,
                                           int node, int lane) {
    float ax = 0.f, ay = 0.f;
    int beg = row_ptr[node], end = row_ptr[node + 1];
    int e = beg;
    for (; e + 8 <= end; e += 8) {
        int2 q[8];
        #pragma unroll
        for (int i = 0; i < 8; i++) q[i] = epack[e + i];
        unsigned p[8];
        #pragma unroll
        for (int i = 0; i < 8; i++) p[i] = H32[(size_t)q[i].x * 64 + lane];
        #pragma unroll
        for (int i = 0; i < 8; i++) {
            float c = __int_as_float(q[i].y);
            ax += c * bflo(p[i]);
            ay += c * bfhi(p[i]);
        }
    }
    for (; e + 4 <= end; e += 4) {
        int2 q0 = epack[e], q1 = epack[e + 1], q2 = epack[e + 2], q3 = epack[e + 3];
        unsigned p0 = H32[(size_t)q0.x * 64 + lane];
        unsigned p1 = H32[(size_t)q1.x * 64 + lane];
        unsigned p2 = H32[(size_t)q2.x * 64 + lane];
        unsigned p3 = H32[(size_t)q3.x * 64 + lane];
        float c0 = __int_as_float(q0.y), c1 = __int_as_float(q1.y);
        float c2 = __int_as_float(q2.y), c3 = __int_as_float(q3.y);
        ax += c0 * bflo(p0) + c1 * bflo(p1) + c2 * bflo(p2) + c3 * bflo(p3);
        ay += c0 * bfhi(p0) + c1 * bfhi(p1) + c2 * bfhi(p2) + c3 * bfhi(p3);
    }
    for (; e < end; e++) {
        int2 q0 = epack[e];
        unsigned p0 = H32[(size_t)q0.x * 64 + lane];
        float c0 = __int_as_float(q0.y);
        ax += c0 * bflo(p0);
        ay += c0 * bfhi(p0);
    }
    float di = dinv[node];
    unsigned ps = H32[(size_t)node * 64 + lane];
    float2 bb = ((const float2*)bias)[lane];
    float2 r;
    r.x = di * ax + di * di * bflo(ps) + bb.x;
    r.y = di * ay + di * di * bfhi(ps) + bb.y;
    return r;
}

// Layer-1 agg: + ReLU, packed bf16 output.
__global__ __launch_bounds__(256) void agg_bf16out_kernel(const unsigned short* __restrict__ H,
                                                          const float* __restrict__ dinv,
                                                          const int* __restrict__ row_ptr,
                                                          const int2* __restrict__ epack,
                                                          const float* __restrict__ bias,
                                                          unsigned* __restrict__ out, int N) {
    int node = (int)((blockIdx.x * (unsigned)blockDim.x + threadIdx.x) >> 6);
    int lane = threadIdx.x & 63;
    if (node >= N) return;
    float2 r = agg_body((const unsigned*)H, dinv, row_ptr, epack, bias, node, lane);
    r.x = fmaxf(r.x, 0.f);
    r.y = fmaxf(r.y, 0.f);
    out[(size_t)node * 64 + lane] = (unsigned)f2bf(r.x) | ((unsigned)f2bf(r.y) << 16);
}

// Layer-2 agg: fp32 output to d_out.
__global__ __launch_bounds__(256) void agg_f32out_kernel(const unsigned short* __restrict__ H,
                                                         const float* __restrict__ dinv,
                                                         const int* __restrict__ row_ptr,
                                                         const int2* __restrict__ epack,
                                                         const float* __restrict__ bias,
                                                         float2* __restrict__ out, int N) {
    int node = (int)((blockIdx.x * (unsigned)blockDim.x + threadIdx.x) >> 6);
    int lane = threadIdx.x & 63;
    if (node >= N) return;
    float2 r = agg_body((const unsigned*)H, dinv, row_ptr, epack, bias, node, lane);
    out[(size_t)node * 64 + lane] = r;
}

extern "C" void kernel_launch(void* const* d_in, const int* in_sizes, int n_in,
                              void* d_out, int out_size, void* d_ws, size_t ws_size,
                              hipStream_t stream) {
    const float* x  = (const float*)d_in[0];
    const int*   ei = (const int*)d_in[1];
    const float* W1 = (const float*)d_in[2];
    const float* b1 = (const float*)d_in[3];
    const float* W2 = (const float*)d_in[4];
    const float* b2 = (const float*)d_in[5];

    int N = in_sizes[0] / D;       // 50000
    int E = in_sizes[1] / 2;       // 600000
    const int* src = ei;
    const int* dst = ei + E;

    char* ws = (char*)d_ws;
    int*   cnt      = (int*)(ws + 0);              // N ints
    int*   row_ptr  = (int*)(ws + 200064);         // N+1 ints
    int*   row_next = (int*)(ws + 400128);         // N+1 ints
    float* dinv     = (float*)(ws + 600192);       // N floats
    int*   bsum     = (int*)(ws + 800256);         // <=256 ints
    int2*  epack    = (int2*)(ws + 801280);        // E int2 (4.8 MB)
    unsigned short* whi1 = (unsigned short*)(ws + 5601280);  // 16384 bf16
    unsigned short* wlo1 = (unsigned short*)(ws + 5634048);
    unsigned short* whi2 = (unsigned short*)(ws + 5666816);
    unsigned short* wlo2 = (unsigned short*)(ws + 5699584);
    unsigned short* hfeat = (unsigned short*)(ws + 5732352);  // N*D bf16 (12.8 MB)
    unsigned short* hmid  = (unsigned short*)(ws + 18532352); // N*D bf16 (12.8 MB)
    float2* outp = (float2*)d_out;

    int nb  = (N + 255) / 256;       // scan blocks (196)
    int eb4 = (E / 4 + 255) / 256;   // 4-edge-per-thread blocks (586)
    int gb  = (N + 63) / 64;         // gemm blocks (782)
    int ab  = (N + 3) / 4;           // agg blocks (4 nodes/block)

    hipMemsetAsync(cnt, 0, (size_t)N * sizeof(int), stream);
    count_wconv_kernel<<<eb4 + 128, 256, 0, stream>>>(dst, cnt, E, W1, W2,
                                                      whi1, wlo1, whi2, wlo2, eb4);
    scan1_kernel<<<nb, 256, 0, stream>>>(cnt, bsum, N);
    scan3_kernel<<<nb, 256, 0, stream>>>(cnt, bsum, row_ptr, row_next, dinv, N, E, nb);

    // fill (CSR scatter) + layer-1 GEMM fused — independent chains overlap
    fill_gemm_kernel<<<eb4 + gb, 256, 0, stream>>>(src, dst, dinv, row_next, epack, E,
                                                   x, whi1, wlo1, hfeat, N, eb4);

    // layer 1 agg + b1 + relu -> hmid (bf16)
    agg_bf16out_kernel<<<ab, 256, 0, stream>>>(hfeat, dinv, row_ptr, epack, b1, (unsigned*)hmid, N);

    // layer 2: h2 = hmid @ W2 ; agg + b2 -> d_out (fp32)
    gemm_bf16a_kernel<<<gb, 256, 0, stream>>>(hmid, whi2, wlo2, hfeat, N);
    agg_f32out_kernel<<<ab, 256, 0, stream>>>(hfeat, dinv, row_ptr, epack, b2, outp, N);
}

// Round 9
// 225.693 us; speedup vs baseline: 1.3430x; 1.0578x over previous
//
#include <hip/hip_runtime.h>
#include <hip/hip_bf16.h>

typedef __attribute__((ext_vector_type(8))) short short8;
typedef __attribute__((ext_vector_type(4))) float floatx4;

#define D 128
#define BCAP 2048       // per-(bucket,sub) capacity; mean fill 383 -> hugely safe
#define CPAD 16         // bcnt padded to 16 ints = 64B line each (kills false sharing)

__device__ __forceinline__ unsigned short f2bf(float f) {
    unsigned u = __float_as_uint(f);
    u += 0x7FFFu + ((u >> 16) & 1u);   // round-to-nearest-even
    return (unsigned short)(u >> 16);
}
__device__ __forceinline__ float bf2f(unsigned short h) {
    return __uint_as_float(((unsigned)h) << 16);
}
__device__ __forceinline__ float bflo(unsigned p) { return __uint_as_float(p << 16); }
__device__ __forceinline__ float bfhi(unsigned p) { return __uint_as_float(p & 0xFFFF0000u); }

// Fused: blocks [0,eb4) bin edges by dst>>8 into 196 buckets x 8 sub-lists
// (sub = blockIdx&7 ~ XCD id -> same-line appends from one XCD). Counter
// array is line-padded: 383 same-line atomics/ctr (vs 24k in round 7).
// Entry = (dst&255)<<16 | src (src < 65536). Blocks [eb4,eb4+128) do wconv.
__global__ __launch_bounds__(256) void bucket_wconv_kernel(const int* __restrict__ src,
                                                           const int* __restrict__ dst,
                                                           int* __restrict__ bcnt,
                                                           unsigned* __restrict__ bucket, int E,
                                                           const float* __restrict__ W1,
                                                           const float* __restrict__ W2,
                                                           unsigned short* __restrict__ whi1,
                                                           unsigned short* __restrict__ wlo1,
                                                           unsigned short* __restrict__ whi2,
                                                           unsigned short* __restrict__ wlo2,
                                                           int eb4) {
    int b = blockIdx.x;
    if (b >= eb4) {
        int gid = (b - eb4) * 256 + threadIdx.x;      // 0..32767
        int which = gid >> 14;
        int tid = gid & 16383;
        const float* W = which ? W2 : W1;
        unsigned short* whi = which ? whi2 : whi1;
        unsigned short* wlo = which ? wlo2 : wlo1;
        int j    = tid & 7;
        int col  = (tid >> 3) & 127;
        int quad = (tid >> 10) & 3;
        int kb   = tid >> 12;
        float wv = W[(kb * 32 + quad * 8 + j) * D + col];
        unsigned u = __float_as_uint(wv);
        unsigned short h = (unsigned short)(u >> 16);          // truncate for hi
        whi[tid] = h;
        wlo[tid] = f2bf(wv - bf2f(h));
        return;
    }
    int sub = b & 7;
    int t4 = (b * 256 + threadIdx.x) * 4;
    if (t4 + 3 < E) {
        int4 s = *reinterpret_cast<const int4*>(src + t4);
        int4 d = *reinterpret_cast<const int4*>(dst + t4);
        #pragma unroll
        for (int k = 0; k < 4; k++) {
            int dd = (k == 0) ? d.x : (k == 1) ? d.y : (k == 2) ? d.z : d.w;
            int ss = (k == 0) ? s.x : (k == 1) ? s.y : (k == 2) ? s.z : s.w;
            int slot = ((dd >> 8) << 3) | sub;
            int pos = atomicAdd(&bcnt[slot * CPAD], 1);
            if (pos < BCAP)
                bucket[(size_t)slot * BCAP + pos] = ((unsigned)(dd & 255) << 16) | (unsigned)ss;
        }
    } else {
        for (int i = t4; i < E; i++) {
            int dd = dst[i], ss = src[i];
            int slot = ((dd >> 8) << 3) | sub;
            int pos = atomicAdd(&bcnt[slot * CPAD], 1);
            if (pos < BCAP)
                bucket[(size_t)slot * BCAP + pos] = ((unsigned)(dd & 255) << 16) | (unsigned)ss;
        }
    }
}

__device__ __forceinline__ int block_excl_scan256(int v, int* lds, int tid) {
    int lane = tid & 63, wid = tid >> 6;
    int x = v;
    #pragma unroll
    for (int d = 1; d < 64; d <<= 1) {
        int y = __shfl_up(x, d, 64);
        if (lane >= d) x += y;
    }
    if (lane == 63) lds[wid] = x;
    __syncthreads();
    if (tid == 0) {
        int run = 0;
        #pragma unroll
        for (int i = 0; i < 4; i++) { int t2 = lds[i]; lds[i] = run; run += t2; }
    }
    __syncthreads();
    return lds[wid] + x - v;   // exclusive prefix within block
}

// One block per bucket: redundant all-bucket base scan (saves a dispatch),
// LDS histogram -> row_ptr/dinv, LDS-offset scatter of sorted src into an
// L2-local ~12KB window (full-line writebacks).
__global__ __launch_bounds__(256) void build_kernel(const unsigned* __restrict__ bucket,
                                                    const int* __restrict__ bcnt,
                                                    int* __restrict__ row_ptr,
                                                    float* __restrict__ dinv,
                                                    int* __restrict__ esrc, int N, int E) {
    __shared__ int lds4[4];
    __shared__ int sbase[256];
    __shared__ int hist[256];
    __shared__ int cur[256];
    int tid = threadIdx.x;
    int b = blockIdx.x;
    int nbuk = gridDim.x;
    int tot = 0;
    if (tid < nbuk) {
        #pragma unroll
        for (int s = 0; s < 8; s++) tot += min(bcnt[(tid * 8 + s) * CPAD], BCAP);
    }
    int ex = block_excl_scan256(tot, lds4, tid);
    sbase[tid] = ex;
    hist[tid] = 0;
    __syncthreads();
    int base = sbase[b];
    // histogram over local dst
    for (int sub = 0; sub < 8; sub++) {
        int cnt = min(bcnt[(b * 8 + sub) * CPAD], BCAP);
        const unsigned* bp = bucket + (size_t)(b * 8 + sub) * BCAP;
        for (int i = tid; i < cnt; i += 256)
            atomicAdd(&hist[bp[i] >> 16], 1);
    }
    __syncthreads();
    int h = hist[tid];
    int off = block_excl_scan256(h, lds4, tid);
    cur[tid] = base + off;
    int node = b * 256 + tid;
    if (node < N) {
        row_ptr[node] = base + off;
        dinv[node] = rsqrtf((float)(h + 1));
    }
    if (b == 0 && tid == 0) row_ptr[N] = E;
    __syncthreads();
    // scatter into [base, base+tot) — hot L2 window, full-line writebacks
    for (int sub = 0; sub < 8; sub++) {
        int cnt = min(bcnt[(b * 8 + sub) * CPAD], BCAP);
        const unsigned* bp = bucket + (size_t)(b * 8 + sub) * BCAP;
        for (int i = tid; i < cnt; i += 256) {
            unsigned v = bp[i];
            int p = atomicAdd(&cur[v >> 16], 1);
            esrc[p] = (int)(v & 0xFFFFu);
        }
    }
}

// Fused: blocks [0,eb4) build epack (coalesced read/write, L2 dinv gather);
// blocks [eb4,eb4+gb) layer-1 GEMM. Independent chains overlap.
__global__ __launch_bounds__(256) void epack_gemm_kernel(const int* __restrict__ esrc,
                                                         const float* __restrict__ dinv,
                                                         int2* __restrict__ epack, int E,
                                                         const float* __restrict__ A,
                                                         const unsigned short* __restrict__ whi,
                                                         const unsigned short* __restrict__ wlo,
                                                         unsigned short* __restrict__ C, int M,
                                                         int eb4) {
    if (blockIdx.x < eb4) {
        int t4 = (blockIdx.x * 256 + threadIdx.x) * 4;
        if (t4 + 3 < E) {
            int4 s = *reinterpret_cast<const int4*>(esrc + t4);
            float c0 = dinv[s.x], c1 = dinv[s.y], c2 = dinv[s.z], c3 = dinv[s.w];
            epack[t4]     = make_int2(s.x, __float_as_int(c0));
            epack[t4 + 1] = make_int2(s.y, __float_as_int(c1));
            epack[t4 + 2] = make_int2(s.z, __float_as_int(c2));
            epack[t4 + 3] = make_int2(s.w, __float_as_int(c3));
        } else {
            for (int i = t4; i < E; i++) {
                int s = esrc[i];
                epack[i] = make_int2(s, __float_as_int(dinv[s]));
            }
        }
        return;
    }
    // ---- layer-1 GEMM: C[M,128](bf16) = A[M,128](fp32) @ W (hi/lo bf16 split)
    int lane = threadIdx.x & 63, wid = threadIdx.x >> 6;
    int quad = lane >> 4, l15 = lane & 15;
    int row0 = (blockIdx.x - eb4) * 64;
    int n0 = wid * 32;

    short8 bhi[2][4], blo[2][4];
    #pragma unroll
    for (int t = 0; t < 2; t++)
        #pragma unroll
        for (int kb = 0; kb < 4; kb++) {
            size_t base = ((size_t)((kb * 4 + quad) * 128 + (n0 + t * 16 + l15))) * 8;
            bhi[t][kb] = *reinterpret_cast<const short8*>(whi + base);
            blo[t][kb] = *reinterpret_cast<const short8*>(wlo + base);
        }

    #pragma unroll
    for (int rg = 0; rg < 4; rg++) {
        int r0 = row0 + rg * 16;
        int ar = r0 + l15; if (ar > M - 1) ar = M - 1;
        short8 ahi[4], alo[4];
        #pragma unroll
        for (int kb = 0; kb < 4; kb++) {
            const float4* ap = reinterpret_cast<const float4*>(A + (size_t)ar * D + kb * 32 + quad * 8);
            float4 v0 = ap[0], v1 = ap[1];
            float vv[8] = {v0.x, v0.y, v0.z, v0.w, v1.x, v1.y, v1.z, v1.w};
            short8 vh, vl;
            #pragma unroll
            for (int j = 0; j < 8; j++) {
                unsigned u = __float_as_uint(vv[j]);
                unsigned short h = (unsigned short)(u >> 16);
                vh[j] = (short)h;
                vl[j] = (short)f2bf(vv[j] - bf2f(h));
            }
            ahi[kb] = vh;
            alo[kb] = vl;
        }
        floatx4 acc0 = {0.f, 0.f, 0.f, 0.f};
        floatx4 acc1 = {0.f, 0.f, 0.f, 0.f};
        #pragma unroll
        for (int kb = 0; kb < 4; kb++) {
            acc0 = __builtin_amdgcn_mfma_f32_16x16x32_bf16(ahi[kb], bhi[0][kb], acc0, 0, 0, 0);
            acc1 = __builtin_amdgcn_mfma_f32_16x16x32_bf16(ahi[kb], bhi[1][kb], acc1, 0, 0, 0);
            acc0 = __builtin_amdgcn_mfma_f32_16x16x32_bf16(ahi[kb], blo[0][kb], acc0, 0, 0, 0);
            acc1 = __builtin_amdgcn_mfma_f32_16x16x32_bf16(ahi[kb], blo[1][kb], acc1, 0, 0, 0);
            acc0 = __builtin_amdgcn_mfma_f32_16x16x32_bf16(alo[kb], bhi[0][kb], acc0, 0, 0, 0);
            acc1 = __builtin_amdgcn_mfma_f32_16x16x32_bf16(alo[kb], bhi[1][kb], acc1, 0, 0, 0);
        }
        #pragma unroll
        for (int r = 0; r < 4; r++) {
            int orow = r0 + quad * 4 + r;
            if (orow < M) {
                C[(size_t)orow * D + n0 + l15]      = f2bf(acc0[r]);
                C[(size_t)orow * D + n0 + 16 + l15] = f2bf(acc1[r]);
            }
        }
    }
}

// Layer-2 GEMM: A already bf16 -> exact; direct short8 loads.
__global__ __launch_bounds__(256) void gemm_bf16a_kernel(const unsigned short* __restrict__ A,
                                                         const unsigned short* __restrict__ whi,
                                                         const unsigned short* __restrict__ wlo,
                                                         unsigned short* __restrict__ C, int M) {
    int lane = threadIdx.x & 63, wid = threadIdx.x >> 6;
    int quad = lane >> 4, l15 = lane & 15;
    int row0 = blockIdx.x * 64;
    int n0 = wid * 32;

    short8 bhi[2][4], blo[2][4];
    #pragma unroll
    for (int t = 0; t < 2; t++)
        #pragma unroll
        for (int kb = 0; kb < 4; kb++) {
            size_t base = ((size_t)((kb * 4 + quad) * 128 + (n0 + t * 16 + l15))) * 8;
            bhi[t][kb] = *reinterpret_cast<const short8*>(whi + base);
            blo[t][kb] = *reinterpret_cast<const short8*>(wlo + base);
        }

    #pragma unroll
    for (int rg = 0; rg < 4; rg++) {
        int r0 = row0 + rg * 16;
        int ar = r0 + l15; if (ar > M - 1) ar = M - 1;
        short8 af[4];
        #pragma unroll
        for (int kb = 0; kb < 4; kb++)
            af[kb] = *reinterpret_cast<const short8*>(A + (size_t)ar * D + kb * 32 + quad * 8);
        floatx4 acc0 = {0.f, 0.f, 0.f, 0.f};
        floatx4 acc1 = {0.f, 0.f, 0.f, 0.f};
        #pragma unroll
        for (int kb = 0; kb < 4; kb++) {
            acc0 = __builtin_amdgcn_mfma_f32_16x16x32_bf16(af[kb], bhi[0][kb], acc0, 0, 0, 0);
            acc1 = __builtin_amdgcn_mfma_f32_16x16x32_bf16(af[kb], bhi[1][kb], acc1, 0, 0, 0);
            acc0 = __builtin_amdgcn_mfma_f32_16x16x32_bf16(af[kb], blo[0][kb], acc0, 0, 0, 0);
            acc1 = __builtin_amdgcn_mfma_f32_16x16x32_bf16(af[kb], blo[1][kb], acc1, 0, 0, 0);
        }
        #pragma unroll
        for (int r = 0; r < 4; r++) {
            int orow = r0 + quad * 4 + r;
            if (orow < M) {
                C[(size_t)orow * D + n0 + l15]      = f2bf(acc0[r]);
                C[(size_t)orow * D + n0 + 16 + l15] = f2bf(acc1[r]);
            }
        }
    }
}

// CSR agg body: 8/4/1-edge unrolled gather loops.
__device__ __forceinline__ float2 agg_body(const unsigned* __restrict__ H32,
                                           const float* __restrict__ dinv,
                                           const int* __restrict__ row_ptr,
                                           const int2* __restrict__ epack,
                                           const float* __restrict__ bias,
                                           int node, int lane) {
    float ax = 0.f, ay = 0.f;
    int beg = row_ptr[node], end = row_ptr[node + 1];
    int e = beg;
    for (; e + 8 <= end; e += 8) {
        int2 q[8];
        #pragma unroll
        for (int i = 0; i < 8; i++) q[i] = epack[e + i];
        unsigned p[8];
        #pragma unroll
        for (int i = 0; i < 8; i++) p[i] = H32[(size_t)q[i].x * 64 + lane];
        #pragma unroll
        for (int i = 0; i < 8; i++) {
            float c = __int_as_float(q[i].y);
            ax += c * bflo(p[i]);
            ay += c * bfhi(p[i]);
        }
    }
    for (; e + 4 <= end; e += 4) {
        int2 q0 = epack[e], q1 = epack[e + 1], q2 = epack[e + 2], q3 = epack[e + 3];
        unsigned p0 = H32[(size_t)q0.x * 64 + lane];
        unsigned p1 = H32[(size_t)q1.x * 64 + lane];
        unsigned p2 = H32[(size_t)q2.x * 64 + lane];
        unsigned p3 = H32[(size_t)q3.x * 64 + lane];
        float c0 = __int_as_float(q0.y), c1 = __int_as_float(q1.y);
        float c2 = __int_as_float(q2.y), c3 = __int_as_float(q3.y);
        ax += c0 * bflo(p0) + c1 * bflo(p1) + c2 * bflo(p2) + c3 * bflo(p3);
        ay += c0 * bfhi(p0) + c1 * bfhi(p1) + c2 * bfhi(p2) + c3 * bfhi(p3);
    }
    for (; e < end; e++) {
        int2 q0 = epack[e];
        unsigned p0 = H32[(size_t)q0.x * 64 + lane];
        float c0 = __int_as_float(q0.y);
        ax += c0 * bflo(p0);
        ay += c0 * bfhi(p0);
    }
    float di = dinv[node];
    unsigned ps = H32[(size_t)node * 64 + lane];
    float2 bb = ((const float2*)bias)[lane];
    float2 r;
    r.x = di * ax + di * di * bflo(ps) + bb.x;
    r.y = di * ay + di * di * bfhi(ps) + bb.y;
    return r;
}

// Layer-1 agg: + ReLU, packed bf16 output.
__global__ __launch_bounds__(256) void agg_bf16out_kernel(const unsigned short* __restrict__ H,
                                                          const float* __restrict__ dinv,
                                                          const int* __restrict__ row_ptr,
                                                          const int2* __restrict__ epack,
                                                          const float* __restrict__ bias,
                                                          unsigned* __restrict__ out, int N) {
    int node = (int)((blockIdx.x * (unsigned)blockDim.x + threadIdx.x) >> 6);
    int lane = threadIdx.x & 63;
    if (node >= N) return;
    float2 r = agg_body((const unsigned*)H, dinv, row_ptr, epack, bias, node, lane);
    r.x = fmaxf(r.x, 0.f);
    r.y = fmaxf(r.y, 0.f);
    out[(size_t)node * 64 + lane] = (unsigned)f2bf(r.x) | ((unsigned)f2bf(r.y) << 16);
}

// Layer-2 agg: fp32 output to d_out.
__global__ __launch_bounds__(256) void agg_f32out_kernel(const unsigned short* __restrict__ H,
                                                         const float* __restrict__ dinv,
                                                         const int* __restrict__ row_ptr,
                                                         const int2* __restrict__ epack,
                                                         const float* __restrict__ bias,
                                                         float2* __restrict__ out, int N) {
    int node = (int)((blockIdx.x * (unsigned)blockDim.x + threadIdx.x) >> 6);
    int lane = threadIdx.x & 63;
    if (node >= N) return;
    float2 r = agg_body((const unsigned*)H, dinv, row_ptr, epack, bias, node, lane);
    out[(size_t)node * 64 + lane] = r;
}

extern "C" void kernel_launch(void* const* d_in, const int* in_sizes, int n_in,
                              void* d_out, int out_size, void* d_ws, size_t ws_size,
                              hipStream_t stream) {
    const float* x  = (const float*)d_in[0];
    const int*   ei = (const int*)d_in[1];
    const float* W1 = (const float*)d_in[2];
    const float* b1 = (const float*)d_in[3];
    const float* W2 = (const float*)d_in[4];
    const float* b2 = (const float*)d_in[5];

    int N = in_sizes[0] / D;       // 50000 (pack requires N <= 65536)
    int E = in_sizes[1] / 2;       // 600000
    const int* src = ei;
    const int* dst = ei + E;

    int nbuk = (N + 255) / 256;    // 196 buckets

    char* ws = (char*)d_ws;
    int*      bcnt   = (int*)(ws + 0);                    // nbuk*8 ctrs, line-padded (100 KB)
    unsigned* bucket = (unsigned*)(ws + 102400);          // nbuk*8*BCAP*4 = 12.85 MB
    int*      row_ptr= (int*)(ws + 12947456);             // N+1 ints
    float*    dinv   = (float*)(ws + 13147520);           // N floats
    int*      esrcs  = (int*)(ws + 13347520);             // E ints (sorted by dst)
    int2*     epack  = (int2*)(ws + 15747584);            // E int2 (4.8 MB)
    unsigned short* whi1 = (unsigned short*)(ws + 20547584);
    unsigned short* wlo1 = (unsigned short*)(ws + 20580352);
    unsigned short* whi2 = (unsigned short*)(ws + 20613120);
    unsigned short* wlo2 = (unsigned short*)(ws + 20645888);
    unsigned short* hfeat = (unsigned short*)(ws + 20678656); // N*D bf16 (12.8 MB)
    unsigned short* hmid  = (unsigned short*)(ws + 33478656); // N*D bf16 (12.8 MB)
    float2* outp = (float2*)d_out;

    int eb4 = (E / 4 + 255) / 256;   // 4-edge-per-thread blocks (586)
    int gb  = (N + 63) / 64;         // gemm blocks (782)
    int ab  = (N + 3) / 4;           // agg blocks (4 nodes/block)

    hipMemsetAsync(bcnt, 0, (size_t)nbuk * 8 * CPAD * sizeof(int), stream);
    bucket_wconv_kernel<<<eb4 + 128, 256, 0, stream>>>(src, dst, bcnt, bucket, E,
                                                       W1, W2, whi1, wlo1, whi2, wlo2, eb4);
    build_kernel<<<nbuk, 256, 0, stream>>>(bucket, bcnt, row_ptr, dinv, esrcs, N, E);

    // epack + layer-1 GEMM fused (independent chains)
    epack_gemm_kernel<<<eb4 + gb, 256, 0, stream>>>(esrcs, dinv, epack, E,
                                                    x, whi1, wlo1, hfeat, N, eb4);

    // layer 1 agg + b1 + relu -> hmid (bf16)
    agg_bf16out_kernel<<<ab, 256, 0, stream>>>(hfeat, dinv, row_ptr, epack, b1, (unsigned*)hmid, N);

    // layer 2: h2 = hmid @ W2 ; agg + b2 -> d_out (fp32)
    gemm_bf16a_kernel<<<gb, 256, 0, stream>>>(hmid, whi2, wlo2, hfeat, N);
    agg_f32out_kernel<<<ab, 256, 0, stream>>>(hfeat, dinv, row_ptr, epack, b2, outp, N);
}

// Round 10
// 216.826 us; speedup vs baseline: 1.3979x; 1.0409x over previous
//
#include <hip/hip_runtime.h>
#include <hip/hip_bf16.h>

typedef __attribute__((ext_vector_type(8))) short short8;
typedef __attribute__((ext_vector_type(4))) float floatx4;

#define D 128
#define BCAP 2048       // per-(bucket,sub) capacity; mean fill 383 -> hugely safe
#define CPAD 16         // bcnt padded to 16 ints = 64B line each (kills false sharing)

__device__ __forceinline__ unsigned short f2bf(float f) {
    unsigned u = __float_as_uint(f);
    u += 0x7FFFu + ((u >> 16) & 1u);   // round-to-nearest-even
    return (unsigned short)(u >> 16);
}
__device__ __forceinline__ float bf2f(unsigned short h) {
    return __uint_as_float(((unsigned)h) << 16);
}
__device__ __forceinline__ float bflo(unsigned p) { return __uint_as_float(p << 16); }
__device__ __forceinline__ float bfhi(unsigned p) { return __uint_as_float(p & 0xFFFF0000u); }

// Fused: blocks [0,eb4) bin edges by dst>>8 into 196 buckets x 8 sub-lists
// (line-padded counters; sub = blockIdx&7 ~ XCD). Blocks [eb4,+128) do wconv.
__global__ __launch_bounds__(256) void bucket_wconv_kernel(const int* __restrict__ src,
                                                           const int* __restrict__ dst,
                                                           int* __restrict__ bcnt,
                                                           unsigned* __restrict__ bucket, int E,
                                                           const float* __restrict__ W1,
                                                           const float* __restrict__ W2,
                                                           unsigned short* __restrict__ whi1,
                                                           unsigned short* __restrict__ wlo1,
                                                           unsigned short* __restrict__ whi2,
                                                           unsigned short* __restrict__ wlo2,
                                                           int eb4) {
    int b = blockIdx.x;
    if (b >= eb4) {
        int gid = (b - eb4) * 256 + threadIdx.x;      // 0..32767
        int which = gid >> 14;
        int tid = gid & 16383;
        const float* W = which ? W2 : W1;
        unsigned short* whi = which ? whi2 : whi1;
        unsigned short* wlo = which ? wlo2 : wlo1;
        int j    = tid & 7;
        int col  = (tid >> 3) & 127;
        int quad = (tid >> 10) & 3;
        int kb   = tid >> 12;
        float wv = W[(kb * 32 + quad * 8 + j) * D + col];
        unsigned u = __float_as_uint(wv);
        unsigned short h = (unsigned short)(u >> 16);          // truncate for hi
        whi[tid] = h;
        wlo[tid] = f2bf(wv - bf2f(h));
        return;
    }
    int sub = b & 7;
    int t4 = (b * 256 + threadIdx.x) * 4;
    if (t4 + 3 < E) {
        int4 s = *reinterpret_cast<const int4*>(src + t4);
        int4 d = *reinterpret_cast<const int4*>(dst + t4);
        #pragma unroll
        for (int k = 0; k < 4; k++) {
            int dd = (k == 0) ? d.x : (k == 1) ? d.y : (k == 2) ? d.z : d.w;
            int ss = (k == 0) ? s.x : (k == 1) ? s.y : (k == 2) ? s.z : s.w;
            int slot = ((dd >> 8) << 3) | sub;
            int pos = atomicAdd(&bcnt[slot * CPAD], 1);
            if (pos < BCAP)
                bucket[(size_t)slot * BCAP + pos] = ((unsigned)(dd & 255) << 16) | (unsigned)ss;
        }
    } else {
        for (int i = t4; i < E; i++) {
            int dd = dst[i], ss = src[i];
            int slot = ((dd >> 8) << 3) | sub;
            int pos = atomicAdd(&bcnt[slot * CPAD], 1);
            if (pos < BCAP)
                bucket[(size_t)slot * BCAP + pos] = ((unsigned)(dd & 255) << 16) | (unsigned)ss;
        }
    }
}

__device__ __forceinline__ int block_excl_scan256(int v, int* lds, int tid) {
    int lane = tid & 63, wid = tid >> 6;
    int x = v;
    #pragma unroll
    for (int d = 1; d < 64; d <<= 1) {
        int y = __shfl_up(x, d, 64);
        if (lane >= d) x += y;
    }
    if (lane == 63) lds[wid] = x;
    __syncthreads();
    if (tid == 0) {
        int run = 0;
        #pragma unroll
        for (int i = 0; i < 4; i++) { int t2 = lds[i]; lds[i] = run; run += t2; }
    }
    __syncthreads();
    return lds[wid] + x - v;   // exclusive prefix within block
}

// One block per bucket: redundant all-bucket base scan, LDS histogram ->
// row_ptr/dinv, LDS-offset scatter into an L2-local ~12KB window.
__global__ __launch_bounds__(256) void build_kernel(const unsigned* __restrict__ bucket,
                                                    const int* __restrict__ bcnt,
                                                    int* __restrict__ row_ptr,
                                                    float* __restrict__ dinv,
                                                    int* __restrict__ esrc, int N, int E) {
    __shared__ int lds4[4];
    __shared__ int sbase[256];
    __shared__ int hist[256];
    __shared__ int cur[256];
    int tid = threadIdx.x;
    int b = blockIdx.x;
    int nbuk = gridDim.x;
    int tot = 0;
    if (tid < nbuk) {
        #pragma unroll
        for (int s = 0; s < 8; s++) tot += min(bcnt[(tid * 8 + s) * CPAD], BCAP);
    }
    int ex = block_excl_scan256(tot, lds4, tid);
    sbase[tid] = ex;
    hist[tid] = 0;
    __syncthreads();
    int base = sbase[b];
    for (int sub = 0; sub < 8; sub++) {
        int cnt = min(bcnt[(b * 8 + sub) * CPAD], BCAP);
        const unsigned* bp = bucket + (size_t)(b * 8 + sub) * BCAP;
        for (int i = tid; i < cnt; i += 256)
            atomicAdd(&hist[bp[i] >> 16], 1);
    }
    __syncthreads();
    int h = hist[tid];
    int off = block_excl_scan256(h, lds4, tid);
    cur[tid] = base + off;
    int node = b * 256 + tid;
    if (node < N) {
        row_ptr[node] = base + off;
        dinv[node] = rsqrtf((float)(h + 1));
    }
    if (b == 0 && tid == 0) row_ptr[N] = E;
    __syncthreads();
    for (int sub = 0; sub < 8; sub++) {
        int cnt = min(bcnt[(b * 8 + sub) * CPAD], BCAP);
        const unsigned* bp = bucket + (size_t)(b * 8 + sub) * BCAP;
        for (int i = tid; i < cnt; i += 256) {
            unsigned v = bp[i];
            int p = atomicAdd(&cur[v >> 16], 1);
            esrc[p] = (int)(v & 0xFFFFu);
        }
    }
}

// Fused: blocks [0,eb4) build epack; blocks [eb4,eb4+gb) layer-1 GEMM.
__global__ __launch_bounds__(256) void epack_gemm_kernel(const int* __restrict__ esrc,
                                                         const float* __restrict__ dinv,
                                                         int2* __restrict__ epack, int E,
                                                         const float* __restrict__ A,
                                                         const unsigned short* __restrict__ whi,
                                                         const unsigned short* __restrict__ wlo,
                                                         unsigned short* __restrict__ C, int M,
                                                         int eb4) {
    if (blockIdx.x < eb4) {
        int t4 = (blockIdx.x * 256 + threadIdx.x) * 4;
        if (t4 + 3 < E) {
            int4 s = *reinterpret_cast<const int4*>(esrc + t4);
            float c0 = dinv[s.x], c1 = dinv[s.y], c2 = dinv[s.z], c3 = dinv[s.w];
            epack[t4]     = make_int2(s.x, __float_as_int(c0));
            epack[t4 + 1] = make_int2(s.y, __float_as_int(c1));
            epack[t4 + 2] = make_int2(s.z, __float_as_int(c2));
            epack[t4 + 3] = make_int2(s.w, __float_as_int(c3));
        } else {
            for (int i = t4; i < E; i++) {
                int s = esrc[i];
                epack[i] = make_int2(s, __float_as_int(dinv[s]));
            }
        }
        return;
    }
    int lane = threadIdx.x & 63, wid = threadIdx.x >> 6;
    int quad = lane >> 4, l15 = lane & 15;
    int row0 = (blockIdx.x - eb4) * 64;
    int n0 = wid * 32;

    short8 bhi[2][4], blo[2][4];
    #pragma unroll
    for (int t = 0; t < 2; t++)
        #pragma unroll
        for (int kb = 0; kb < 4; kb++) {
            size_t base = ((size_t)((kb * 4 + quad) * 128 + (n0 + t * 16 + l15))) * 8;
            bhi[t][kb] = *reinterpret_cast<const short8*>(whi + base);
            blo[t][kb] = *reinterpret_cast<const short8*>(wlo + base);
        }

    #pragma unroll
    for (int rg = 0; rg < 4; rg++) {
        int r0 = row0 + rg * 16;
        int ar = r0 + l15; if (ar > M - 1) ar = M - 1;
        short8 ahi[4], alo[4];
        #pragma unroll
        for (int kb = 0; kb < 4; kb++) {
            const float4* ap = reinterpret_cast<const float4*>(A + (size_t)ar * D + kb * 32 + quad * 8);
            float4 v0 = ap[0], v1 = ap[1];
            float vv[8] = {v0.x, v0.y, v0.z, v0.w, v1.x, v1.y, v1.z, v1.w};
            short8 vh, vl;
            #pragma unroll
            for (int j = 0; j < 8; j++) {
                unsigned u = __float_as_uint(vv[j]);
                unsigned short h = (unsigned short)(u >> 16);
                vh[j] = (short)h;
                vl[j] = (short)f2bf(vv[j] - bf2f(h));
            }
            ahi[kb] = vh;
            alo[kb] = vl;
        }
        floatx4 acc0 = {0.f, 0.f, 0.f, 0.f};
        floatx4 acc1 = {0.f, 0.f, 0.f, 0.f};
        #pragma unroll
        for (int kb = 0; kb < 4; kb++) {
            acc0 = __builtin_amdgcn_mfma_f32_16x16x32_bf16(ahi[kb], bhi[0][kb], acc0, 0, 0, 0);
            acc1 = __builtin_amdgcn_mfma_f32_16x16x32_bf16(ahi[kb], bhi[1][kb], acc1, 0, 0, 0);
            acc0 = __builtin_amdgcn_mfma_f32_16x16x32_bf16(ahi[kb], blo[0][kb], acc0, 0, 0, 0);
            acc1 = __builtin_amdgcn_mfma_f32_16x16x32_bf16(ahi[kb], blo[1][kb], acc1, 0, 0, 0);
            acc0 = __builtin_amdgcn_mfma_f32_16x16x32_bf16(alo[kb], bhi[0][kb], acc0, 0, 0, 0);
            acc1 = __builtin_amdgcn_mfma_f32_16x16x32_bf16(alo[kb], bhi[1][kb], acc1, 0, 0, 0);
        }
        #pragma unroll
        for (int r = 0; r < 4; r++) {
            int orow = r0 + quad * 4 + r;
            if (orow < M) {
                C[(size_t)orow * D + n0 + l15]      = f2bf(acc0[r]);
                C[(size_t)orow * D + n0 + 16 + l15] = f2bf(acc1[r]);
            }
        }
    }
}

// Layer-2 GEMM: A already bf16 -> exact; direct short8 loads.
__global__ __launch_bounds__(256) void gemm_bf16a_kernel(const unsigned short* __restrict__ A,
                                                         const unsigned short* __restrict__ whi,
                                                         const unsigned short* __restrict__ wlo,
                                                         unsigned short* __restrict__ C, int M) {
    int lane = threadIdx.x & 63, wid = threadIdx.x >> 6;
    int quad = lane >> 4, l15 = lane & 15;
    int row0 = blockIdx.x * 64;
    int n0 = wid * 32;

    short8 bhi[2][4], blo[2][4];
    #pragma unroll
    for (int t = 0; t < 2; t++)
        #pragma unroll
        for (int kb = 0; kb < 4; kb++) {
            size_t base = ((size_t)((kb * 4 + quad) * 128 + (n0 + t * 16 + l15))) * 8;
            bhi[t][kb] = *reinterpret_cast<const short8*>(whi + base);
            blo[t][kb] = *reinterpret_cast<const short8*>(wlo + base);
        }

    #pragma unroll
    for (int rg = 0; rg < 4; rg++) {
        int r0 = row0 + rg * 16;
        int ar = r0 + l15; if (ar > M - 1) ar = M - 1;
        short8 af[4];
        #pragma unroll
        for (int kb = 0; kb < 4; kb++)
            af[kb] = *reinterpret_cast<const short8*>(A + (size_t)ar * D + kb * 32 + quad * 8);
        floatx4 acc0 = {0.f, 0.f, 0.f, 0.f};
        floatx4 acc1 = {0.f, 0.f, 0.f, 0.f};
        #pragma unroll
        for (int kb = 0; kb < 4; kb++) {
            acc0 = __builtin_amdgcn_mfma_f32_16x16x32_bf16(af[kb], bhi[0][kb], acc0, 0, 0, 0);
            acc1 = __builtin_amdgcn_mfma_f32_16x16x32_bf16(af[kb], bhi[1][kb], acc1, 0, 0, 0);
            acc0 = __builtin_amdgcn_mfma_f32_16x16x32_bf16(af[kb], blo[0][kb], acc0, 0, 0, 0);
            acc1 = __builtin_amdgcn_mfma_f32_16x16x32_bf16(af[kb], blo[1][kb], acc1, 0, 0, 0);
        }
        #pragma unroll
        for (int r = 0; r < 4; r++) {
            int orow = r0 + quad * 4 + r;
            if (orow < M) {
                C[(size_t)orow * D + n0 + l15]      = f2bf(acc0[r]);
                C[(size_t)orow * D + n0 + 16 + l15] = f2bf(acc1[r]);
            }
        }
    }
}

// Quarter-wave agg: 4 nodes/wave, 16 lanes/node, lane owns 8 features via one
// uint4 (16B) load per edge. 4x fewer memory instructions per edge than
// 64-lane version; 4 independent edge streams per wave.
__device__ __forceinline__ void agg_qbody(const uint4* __restrict__ H4,
                                          const float* __restrict__ dinv,
                                          const int* __restrict__ row_ptr,
                                          const int2* __restrict__ epack,
                                          const float* __restrict__ bias,
                                          int node, int fl, float* acc) {
    #pragma unroll
    for (int j = 0; j < 8; j++) acc[j] = 0.f;
    int beg = row_ptr[node], end = row_ptr[node + 1];
    int e = beg;
    for (; e + 4 <= end; e += 4) {
        int2 q[4];
        #pragma unroll
        for (int i = 0; i < 4; i++) q[i] = epack[e + i];
        uint4 p[4];
        #pragma unroll
        for (int i = 0; i < 4; i++) p[i] = H4[(size_t)q[i].x * 16 + fl];
        #pragma unroll
        for (int i = 0; i < 4; i++) {
            float c = __int_as_float(q[i].y);
            acc[0] += c * bflo(p[i].x); acc[1] += c * bfhi(p[i].x);
            acc[2] += c * bflo(p[i].y); acc[3] += c * bfhi(p[i].y);
            acc[4] += c * bflo(p[i].z); acc[5] += c * bfhi(p[i].z);
            acc[6] += c * bflo(p[i].w); acc[7] += c * bfhi(p[i].w);
        }
    }
    for (; e < end; e++) {
        int2 q0 = epack[e];
        uint4 p0 = H4[(size_t)q0.x * 16 + fl];
        float c = __int_as_float(q0.y);
        acc[0] += c * bflo(p0.x); acc[1] += c * bfhi(p0.x);
        acc[2] += c * bflo(p0.y); acc[3] += c * bfhi(p0.y);
        acc[4] += c * bflo(p0.z); acc[5] += c * bfhi(p0.z);
        acc[6] += c * bflo(p0.w); acc[7] += c * bfhi(p0.w);
    }
    float di = dinv[node];
    float dii = di * di;
    uint4 ps = H4[(size_t)node * 16 + fl];
    const float4* b4 = (const float4*)bias;
    float4 bb0 = b4[fl * 2], bb1 = b4[fl * 2 + 1];
    #pragma unroll
    for (int j = 0; j < 8; j++) acc[j] *= di;
    acc[0] += dii * bflo(ps.x) + bb0.x;
    acc[1] += dii * bfhi(ps.x) + bb0.y;
    acc[2] += dii * bflo(ps.y) + bb0.z;
    acc[3] += dii * bfhi(ps.y) + bb0.w;
    acc[4] += dii * bflo(ps.z) + bb1.x;
    acc[5] += dii * bfhi(ps.z) + bb1.y;
    acc[6] += dii * bflo(ps.w) + bb1.z;
    acc[7] += dii * bfhi(ps.w) + bb1.w;
}

// Layer-1 agg: + ReLU, packed bf16 uint4 (16B) output.
__global__ __launch_bounds__(256) void agg_bf16out_kernel(const unsigned short* __restrict__ H,
                                                          const float* __restrict__ dinv,
                                                          const int* __restrict__ row_ptr,
                                                          const int2* __restrict__ epack,
                                                          const float* __restrict__ bias,
                                                          uint4* __restrict__ out, int N) {
    int node = blockIdx.x * 16 + (threadIdx.x >> 4);
    int fl = threadIdx.x & 15;
    if (node >= N) return;
    float acc[8];
    agg_qbody((const uint4*)H, dinv, row_ptr, epack, bias, node, fl, acc);
    uint4 o;
    o.x = (unsigned)f2bf(fmaxf(acc[0], 0.f)) | ((unsigned)f2bf(fmaxf(acc[1], 0.f)) << 16);
    o.y = (unsigned)f2bf(fmaxf(acc[2], 0.f)) | ((unsigned)f2bf(fmaxf(acc[3], 0.f)) << 16);
    o.z = (unsigned)f2bf(fmaxf(acc[4], 0.f)) | ((unsigned)f2bf(fmaxf(acc[5], 0.f)) << 16);
    o.w = (unsigned)f2bf(fmaxf(acc[6], 0.f)) | ((unsigned)f2bf(fmaxf(acc[7], 0.f)) << 16);
    out[(size_t)node * 16 + fl] = o;
}

// Layer-2 agg: fp32 float4 x2 output to d_out.
__global__ __launch_bounds__(256) void agg_f32out_kernel(const unsigned short* __restrict__ H,
                                                         const float* __restrict__ dinv,
                                                         const int* __restrict__ row_ptr,
                                                         const int2* __restrict__ epack,
                                                         const float* __restrict__ bias,
                                                         float4* __restrict__ out, int N) {
    int node = blockIdx.x * 16 + (threadIdx.x >> 4);
    int fl = threadIdx.x & 15;
    if (node >= N) return;
    float acc[8];
    agg_qbody((const uint4*)H, dinv, row_ptr, epack, bias, node, fl, acc);
    float4 o0, o1;
    o0.x = acc[0]; o0.y = acc[1]; o0.z = acc[2]; o0.w = acc[3];
    o1.x = acc[4]; o1.y = acc[5]; o1.z = acc[6]; o1.w = acc[7];
    out[(size_t)node * 32 + fl * 2]     = o0;
    out[(size_t)node * 32 + fl * 2 + 1] = o1;
}

extern "C" void kernel_launch(void* const* d_in, const int* in_sizes, int n_in,
                              void* d_out, int out_size, void* d_ws, size_t ws_size,
                              hipStream_t stream) {
    const float* x  = (const float*)d_in[0];
    const int*   ei = (const int*)d_in[1];
    const float* W1 = (const float*)d_in[2];
    const float* b1 = (const float*)d_in[3];
    const float* W2 = (const float*)d_in[4];
    const float* b2 = (const float*)d_in[5];

    int N = in_sizes[0] / D;       // 50000 (pack requires N <= 65536)
    int E = in_sizes[1] / 2;       // 600000
    const int* src = ei;
    const int* dst = ei + E;

    int nbuk = (N + 255) / 256;    // 196 buckets

    char* ws = (char*)d_ws;
    int*      bcnt   = (int*)(ws + 0);                    // nbuk*8 ctrs, line-padded (100 KB)
    unsigned* bucket = (unsigned*)(ws + 102400);          // nbuk*8*BCAP*4 = 12.85 MB
    int*      row_ptr= (int*)(ws + 12947456);             // N+1 ints
    float*    dinv   = (float*)(ws + 13147520);           // N floats
    int*      esrcs  = (int*)(ws + 13347520);             // E ints (sorted by dst)
    int2*     epack  = (int2*)(ws + 15747584);            // E int2 (4.8 MB)
    unsigned short* whi1 = (unsigned short*)(ws + 20547584);
    unsigned short* wlo1 = (unsigned short*)(ws + 20580352);
    unsigned short* whi2 = (unsigned short*)(ws + 20613120);
    unsigned short* wlo2 = (unsigned short*)(ws + 20645888);
    unsigned short* hfeat = (unsigned short*)(ws + 20678656); // N*D bf16 (12.8 MB)
    unsigned short* hmid  = (unsigned short*)(ws + 33478656); // N*D bf16 (12.8 MB)

    int eb4  = (E / 4 + 255) / 256;   // 4-edge-per-thread blocks (586)
    int gb   = (N + 63) / 64;         // gemm blocks (782)
    int ab16 = (N + 15) / 16;         // agg blocks (16 nodes/block)

    hipMemsetAsync(bcnt, 0, (size_t)nbuk * 8 * CPAD * sizeof(int), stream);
    bucket_wconv_kernel<<<eb4 + 128, 256, 0, stream>>>(src, dst, bcnt, bucket, E,
                                                       W1, W2, whi1, wlo1, whi2, wlo2, eb4);
    build_kernel<<<nbuk, 256, 0, stream>>>(bucket, bcnt, row_ptr, dinv, esrcs, N, E);

    // epack + layer-1 GEMM fused (independent chains)
    epack_gemm_kernel<<<eb4 + gb, 256, 0, stream>>>(esrcs, dinv, epack, E,
                                                    x, whi1, wlo1, hfeat, N, eb4);

    // layer 1 agg + b1 + relu -> hmid (bf16)
    agg_bf16out_kernel<<<ab16, 256, 0, stream>>>(hfeat, dinv, row_ptr, epack, b1,
                                                 (uint4*)hmid, N);

    // layer 2: h2 = hmid @ W2 ; agg + b2 -> d_out (fp32)
    gemm_bf16a_kernel<<<gb, 256, 0, stream>>>(hmid, whi2, wlo2, hfeat, N);
    agg_f32out_kernel<<<ab16, 256, 0, stream>>>(hfeat, dinv, row_ptr, epack, b2,
                                                (float4*)d_out, N);
}

// Round 11
// 203.760 us; speedup vs baseline: 1.4876x; 1.0641x over previous
//
#include <hip/hip_runtime.h>
#include <hip/hip_bf16.h>

typedef __attribute__((ext_vector_type(8))) short short8;
typedef __attribute__((ext_vector_type(4))) float floatx4;

#define D 128
#define BCAP 2048       // per-(bucket,sub) capacity; mean fill 383 -> hugely safe
#define CPAD 16         // bcnt padded to 16 ints = one line each (kills false sharing)

__device__ __forceinline__ unsigned short f2bf(float f) {
    unsigned u = __float_as_uint(f);
    u += 0x7FFFu + ((u >> 16) & 1u);   // round-to-nearest-even
    return (unsigned short)(u >> 16);
}
__device__ __forceinline__ float bf2f(unsigned short h) {
    return __uint_as_float(((unsigned)h) << 16);
}
__device__ __forceinline__ float bflo(unsigned p) { return __uint_as_float(p << 16); }
__device__ __forceinline__ float bfhi(unsigned p) { return __uint_as_float(p & 0xFFFF0000u); }

// Fused: blocks [0,eb4) bin edges by dst>>8 into 196 buckets x 8 sub-lists
// (line-padded counters; sub = blockIdx&7 ~ XCD). Blocks [eb4,+128) do wconv.
__global__ __launch_bounds__(256) void bucket_wconv_kernel(const int* __restrict__ src,
                                                           const int* __restrict__ dst,
                                                           int* __restrict__ bcnt,
                                                           unsigned* __restrict__ bucket, int E,
                                                           const float* __restrict__ W1,
                                                           const float* __restrict__ W2,
                                                           unsigned short* __restrict__ whi1,
                                                           unsigned short* __restrict__ wlo1,
                                                           unsigned short* __restrict__ whi2,
                                                           unsigned short* __restrict__ wlo2,
                                                           int eb4) {
    int b = blockIdx.x;
    if (b >= eb4) {
        int gid = (b - eb4) * 256 + threadIdx.x;      // 0..32767
        int which = gid >> 14;
        int tid = gid & 16383;
        const float* W = which ? W2 : W1;
        unsigned short* whi = which ? whi2 : whi1;
        unsigned short* wlo = which ? wlo2 : wlo1;
        int j    = tid & 7;
        int col  = (tid >> 3) & 127;
        int quad = (tid >> 10) & 3;
        int kb   = tid >> 12;
        float wv = W[(kb * 32 + quad * 8 + j) * D + col];
        unsigned u = __float_as_uint(wv);
        unsigned short h = (unsigned short)(u >> 16);          // truncate for hi
        whi[tid] = h;
        wlo[tid] = f2bf(wv - bf2f(h));
        return;
    }
    int sub = b & 7;
    int t4 = (b * 256 + threadIdx.x) * 4;
    if (t4 + 3 < E) {
        int4 s = *reinterpret_cast<const int4*>(src + t4);
        int4 d = *reinterpret_cast<const int4*>(dst + t4);
        #pragma unroll
        for (int k = 0; k < 4; k++) {
            int dd = (k == 0) ? d.x : (k == 1) ? d.y : (k == 2) ? d.z : d.w;
            int ss = (k == 0) ? s.x : (k == 1) ? s.y : (k == 2) ? s.z : s.w;
            int slot = ((dd >> 8) << 3) | sub;
            int pos = atomicAdd(&bcnt[slot * CPAD], 1);
            if (pos < BCAP)
                bucket[(size_t)slot * BCAP + pos] = ((unsigned)(dd & 255) << 16) | (unsigned)ss;
        }
    } else {
        for (int i = t4; i < E; i++) {
            int dd = dst[i], ss = src[i];
            int slot = ((dd >> 8) << 3) | sub;
            int pos = atomicAdd(&bcnt[slot * CPAD], 1);
            if (pos < BCAP)
                bucket[(size_t)slot * BCAP + pos] = ((unsigned)(dd & 255) << 16) | (unsigned)ss;
        }
    }
}

__device__ __forceinline__ int block_excl_scan256(int v, int* lds, int tid) {
    int lane = tid & 63, wid = tid >> 6;
    int x = v;
    #pragma unroll
    for (int d = 1; d < 64; d <<= 1) {
        int y = __shfl_up(x, d, 64);
        if (lane >= d) x += y;
    }
    if (lane == 63) lds[wid] = x;
    __syncthreads();
    if (tid == 0) {
        int run = 0;
        #pragma unroll
        for (int i = 0; i < 4; i++) { int t2 = lds[i]; lds[i] = run; run += t2; }
    }
    __syncthreads();
    return lds[wid] + x - v;   // exclusive prefix within block
}

// Fused: blocks [0,nbuk) build the CSR (redundant all-bucket base scan, LDS
// histogram -> row_ptr/dinv, L2-local scatter of sorted src); blocks
// [nbuk, nbuk+gb) do the layer-1 GEMM (needs only wconv output) — independent
// chains overlap: build's LDS-atomic latency hides under GEMM compute.
__global__ __launch_bounds__(256) void build_gemm_kernel(const unsigned* __restrict__ bucket,
                                                         const int* __restrict__ bcnt,
                                                         int* __restrict__ row_ptr,
                                                         float* __restrict__ dinv,
                                                         int* __restrict__ esrc, int N, int E,
                                                         const float* __restrict__ A,
                                                         const unsigned short* __restrict__ whi,
                                                         const unsigned short* __restrict__ wlo,
                                                         unsigned short* __restrict__ C, int M,
                                                         int nbuk) {
    __shared__ int lds4[4];
    __shared__ int sbase[256];
    __shared__ int hist[256];
    __shared__ int cur[256];
    int tid = threadIdx.x;
    int b = blockIdx.x;
    if (b < nbuk) {
        int tot = 0;
        if (tid < nbuk) {
            #pragma unroll
            for (int s = 0; s < 8; s++) tot += min(bcnt[(tid * 8 + s) * CPAD], BCAP);
        }
        int ex = block_excl_scan256(tot, lds4, tid);
        sbase[tid] = ex;
        hist[tid] = 0;
        __syncthreads();
        int base = sbase[b];
        for (int sub = 0; sub < 8; sub++) {
            int cnt = min(bcnt[(b * 8 + sub) * CPAD], BCAP);
            const unsigned* bp = bucket + (size_t)(b * 8 + sub) * BCAP;
            for (int i = tid; i < cnt; i += 256)
                atomicAdd(&hist[bp[i] >> 16], 1);
        }
        __syncthreads();
        int h = hist[tid];
        int off = block_excl_scan256(h, lds4, tid);
        cur[tid] = base + off;
        int node = b * 256 + tid;
        if (node < N) {
            row_ptr[node] = base + off;
            dinv[node] = rsqrtf((float)(h + 1));
        }
        if (b == 0 && tid == 0) row_ptr[N] = E;
        __syncthreads();
        for (int sub = 0; sub < 8; sub++) {
            int cnt = min(bcnt[(b * 8 + sub) * CPAD], BCAP);
            const unsigned* bp = bucket + (size_t)(b * 8 + sub) * BCAP;
            for (int i = tid; i < cnt; i += 256) {
                unsigned v = bp[i];
                int p = atomicAdd(&cur[v >> 16], 1);
                esrc[p] = (int)(v & 0xFFFFu);
            }
        }
        return;
    }
    // ---- layer-1 GEMM: C[M,128](bf16) = A[M,128](fp32) @ W (hi/lo bf16 split)
    int lane = tid & 63, wid = tid >> 6;
    int quad = lane >> 4, l15 = lane & 15;
    int row0 = (b - nbuk) * 64;
    int n0 = wid * 32;

    short8 bhi[2][4], blo[2][4];
    #pragma unroll
    for (int t = 0; t < 2; t++)
        #pragma unroll
        for (int kb = 0; kb < 4; kb++) {
            size_t base = ((size_t)((kb * 4 + quad) * 128 + (n0 + t * 16 + l15))) * 8;
            bhi[t][kb] = *reinterpret_cast<const short8*>(whi + base);
            blo[t][kb] = *reinterpret_cast<const short8*>(wlo + base);
        }

    #pragma unroll
    for (int rg = 0; rg < 4; rg++) {
        int r0 = row0 + rg * 16;
        int ar = r0 + l15; if (ar > M - 1) ar = M - 1;
        short8 ahi[4], alo[4];
        #pragma unroll
        for (int kb = 0; kb < 4; kb++) {
            const float4* ap = reinterpret_cast<const float4*>(A + (size_t)ar * D + kb * 32 + quad * 8);
            float4 v0 = ap[0], v1 = ap[1];
            float vv[8] = {v0.x, v0.y, v0.z, v0.w, v1.x, v1.y, v1.z, v1.w};
            short8 vh, vl;
            #pragma unroll
            for (int j = 0; j < 8; j++) {
                unsigned u = __float_as_uint(vv[j]);
                unsigned short h = (unsigned short)(u >> 16);
                vh[j] = (short)h;
                vl[j] = (short)f2bf(vv[j] - bf2f(h));
            }
            ahi[kb] = vh;
            alo[kb] = vl;
        }
        floatx4 acc0 = {0.f, 0.f, 0.f, 0.f};
        floatx4 acc1 = {0.f, 0.f, 0.f, 0.f};
        #pragma unroll
        for (int kb = 0; kb < 4; kb++) {
            acc0 = __builtin_amdgcn_mfma_f32_16x16x32_bf16(ahi[kb], bhi[0][kb], acc0, 0, 0, 0);
            acc1 = __builtin_amdgcn_mfma_f32_16x16x32_bf16(ahi[kb], bhi[1][kb], acc1, 0, 0, 0);
            acc0 = __builtin_amdgcn_mfma_f32_16x16x32_bf16(ahi[kb], blo[0][kb], acc0, 0, 0, 0);
            acc1 = __builtin_amdgcn_mfma_f32_16x16x32_bf16(ahi[kb], blo[1][kb], acc1, 0, 0, 0);
            acc0 = __builtin_amdgcn_mfma_f32_16x16x32_bf16(alo[kb], bhi[0][kb], acc0, 0, 0, 0);
            acc1 = __builtin_amdgcn_mfma_f32_16x16x32_bf16(alo[kb], bhi[1][kb], acc1, 0, 0, 0);
        }
        #pragma unroll
        for (int r = 0; r < 4; r++) {
            int orow = r0 + quad * 4 + r;
            if (orow < M) {
                C[(size_t)orow * D + n0 + l15]      = f2bf(acc0[r]);
                C[(size_t)orow * D + n0 + 16 + l15] = f2bf(acc1[r]);
            }
        }
    }
}

// Layer-2 GEMM: A already bf16 -> exact; direct short8 loads.
__global__ __launch_bounds__(256) void gemm_bf16a_kernel(const unsigned short* __restrict__ A,
                                                         const unsigned short* __restrict__ whi,
                                                         const unsigned short* __restrict__ wlo,
                                                         unsigned short* __restrict__ C, int M) {
    int lane = threadIdx.x & 63, wid = threadIdx.x >> 6;
    int quad = lane >> 4, l15 = lane & 15;
    int row0 = blockIdx.x * 64;
    int n0 = wid * 32;

    short8 bhi[2][4], blo[2][4];
    #pragma unroll
    for (int t = 0; t < 2; t++)
        #pragma unroll
        for (int kb = 0; kb < 4; kb++) {
            size_t base = ((size_t)((kb * 4 + quad) * 128 + (n0 + t * 16 + l15))) * 8;
            bhi[t][kb] = *reinterpret_cast<const short8*>(whi + base);
            blo[t][kb] = *reinterpret_cast<const short8*>(wlo + base);
        }

    #pragma unroll
    for (int rg = 0; rg < 4; rg++) {
        int r0 = row0 + rg * 16;
        int ar = r0 + l15; if (ar > M - 1) ar = M - 1;
        short8 af[4];
        #pragma unroll
        for (int kb = 0; kb < 4; kb++)
            af[kb] = *reinterpret_cast<const short8*>(A + (size_t)ar * D + kb * 32 + quad * 8);
        floatx4 acc0 = {0.f, 0.f, 0.f, 0.f};
        floatx4 acc1 = {0.f, 0.f, 0.f, 0.f};
        #pragma unroll
        for (int kb = 0; kb < 4; kb++) {
            acc0 = __builtin_amdgcn_mfma_f32_16x16x32_bf16(af[kb], bhi[0][kb], acc0, 0, 0, 0);
            acc1 = __builtin_amdgcn_mfma_f32_16x16x32_bf16(af[kb], bhi[1][kb], acc1, 0, 0, 0);
            acc0 = __builtin_amdgcn_mfma_f32_16x16x32_bf16(af[kb], blo[0][kb], acc0, 0, 0, 0);
            acc1 = __builtin_amdgcn_mfma_f32_16x16x32_bf16(af[kb], blo[1][kb], acc1, 0, 0, 0);
        }
        #pragma unroll
        for (int r = 0; r < 4; r++) {
            int orow = r0 + quad * 4 + r;
            if (orow < M) {
                C[(size_t)orow * D + n0 + l15]      = f2bf(acc0[r]);
                C[(size_t)orow * D + n0 + 16 + l15] = f2bf(acc1[r]);
            }
        }
    }
}

// Quarter-wave agg, epack-free: 4 nodes/wave, 16 lanes/node, lane owns 8
// features via one uint4 (16B) load per edge. esrc[e] and dinv[s] are
// broadcast loads (16 lanes same addr); dinv gather overlaps the H gather.
__device__ __forceinline__ void agg_qbody(const uint4* __restrict__ H4,
                                          const float* __restrict__ dinv,
                                          const int* __restrict__ row_ptr,
                                          const int* __restrict__ esrc,
                                          const float* __restrict__ bias,
                                          int node, int fl, float* acc) {
    #pragma unroll
    for (int j = 0; j < 8; j++) acc[j] = 0.f;
    int beg = row_ptr[node], end = row_ptr[node + 1];
    int e = beg;
    for (; e + 4 <= end; e += 4) {
        int s0 = esrc[e], s1 = esrc[e + 1], s2 = esrc[e + 2], s3 = esrc[e + 3];
        float c0 = dinv[s0], c1 = dinv[s1], c2 = dinv[s2], c3 = dinv[s3];
        uint4 p0 = H4[(size_t)s0 * 16 + fl];
        uint4 p1 = H4[(size_t)s1 * 16 + fl];
        uint4 p2 = H4[(size_t)s2 * 16 + fl];
        uint4 p3 = H4[(size_t)s3 * 16 + fl];
        acc[0] += c0 * bflo(p0.x) + c1 * bflo(p1.x) + c2 * bflo(p2.x) + c3 * bflo(p3.x);
        acc[1] += c0 * bfhi(p0.x) + c1 * bfhi(p1.x) + c2 * bfhi(p2.x) + c3 * bfhi(p3.x);
        acc[2] += c0 * bflo(p0.y) + c1 * bflo(p1.y) + c2 * bflo(p2.y) + c3 * bflo(p3.y);
        acc[3] += c0 * bfhi(p0.y) + c1 * bfhi(p1.y) + c2 * bfhi(p2.y) + c3 * bfhi(p3.y);
        acc[4] += c0 * bflo(p0.z) + c1 * bflo(p1.z) + c2 * bflo(p2.z) + c3 * bflo(p3.z);
        acc[5] += c0 * bfhi(p0.z) + c1 * bfhi(p1.z) + c2 * bfhi(p2.z) + c3 * bfhi(p3.z);
        acc[6] += c0 * bflo(p0.w) + c1 * bflo(p1.w) + c2 * bflo(p2.w) + c3 * bflo(p3.w);
        acc[7] += c0 * bfhi(p0.w) + c1 * bfhi(p1.w) + c2 * bfhi(p2.w) + c3 * bfhi(p3.w);
    }
    for (; e < end; e++) {
        int s0 = esrc[e];
        float c = dinv[s0];
        uint4 p0 = H4[(size_t)s0 * 16 + fl];
        acc[0] += c * bflo(p0.x); acc[1] += c * bfhi(p0.x);
        acc[2] += c * bflo(p0.y); acc[3] += c * bfhi(p0.y);
        acc[4] += c * bflo(p0.z); acc[5] += c * bfhi(p0.z);
        acc[6] += c * bflo(p0.w); acc[7] += c * bfhi(p0.w);
    }
    float di = dinv[node];
    float dii = di * di;
    uint4 ps = H4[(size_t)node * 16 + fl];
    const float4* b4 = (const float4*)bias;
    float4 bb0 = b4[fl * 2], bb1 = b4[fl * 2 + 1];
    #pragma unroll
    for (int j = 0; j < 8; j++) acc[j] *= di;
    acc[0] += dii * bflo(ps.x) + bb0.x;
    acc[1] += dii * bfhi(ps.x) + bb0.y;
    acc[2] += dii * bflo(ps.y) + bb0.z;
    acc[3] += dii * bfhi(ps.y) + bb0.w;
    acc[4] += dii * bflo(ps.z) + bb1.x;
    acc[5] += dii * bfhi(ps.z) + bb1.y;
    acc[6] += dii * bflo(ps.w) + bb1.z;
    acc[7] += dii * bfhi(ps.w) + bb1.w;
}

// Layer-1 agg: + ReLU, packed bf16 uint4 (16B) output.
__global__ __launch_bounds__(256) void agg_bf16out_kernel(const unsigned short* __restrict__ H,
                                                          const float* __restrict__ dinv,
                                                          const int* __restrict__ row_ptr,
                                                          const int* __restrict__ esrc,
                                                          const float* __restrict__ bias,
                                                          uint4* __restrict__ out, int N) {
    int node = blockIdx.x * 16 + (threadIdx.x >> 4);
    int fl = threadIdx.x & 15;
    if (node >= N) return;
    float acc[8];
    agg_qbody((const uint4*)H, dinv, row_ptr, esrc, bias, node, fl, acc);
    uint4 o;
    o.x = (unsigned)f2bf(fmaxf(acc[0], 0.f)) | ((unsigned)f2bf(fmaxf(acc[1], 0.f)) << 16);
    o.y = (unsigned)f2bf(fmaxf(acc[2], 0.f)) | ((unsigned)f2bf(fmaxf(acc[3], 0.f)) << 16);
    o.z = (unsigned)f2bf(fmaxf(acc[4], 0.f)) | ((unsigned)f2bf(fmaxf(acc[5], 0.f)) << 16);
    o.w = (unsigned)f2bf(fmaxf(acc[6], 0.f)) | ((unsigned)f2bf(fmaxf(acc[7], 0.f)) << 16);
    out[(size_t)node * 16 + fl] = o;
}

// Layer-2 agg: fp32 float4 x2 output to d_out.
__global__ __launch_bounds__(256) void agg_f32out_kernel(const unsigned short* __restrict__ H,
                                                         const float* __restrict__ dinv,
                                                         const int* __restrict__ row_ptr,
                                                         const int* __restrict__ esrc,
                                                         const float* __restrict__ bias,
                                                         float4* __restrict__ out, int N) {
    int node = blockIdx.x * 16 + (threadIdx.x >> 4);
    int fl = threadIdx.x & 15;
    if (node >= N) return;
    float acc[8];
    agg_qbody((const uint4*)H, dinv, row_ptr, esrc, bias, node, fl, acc);
    float4 o0, o1;
    o0.x = acc[0]; o0.y = acc[1]; o0.z = acc[2]; o0.w = acc[3];
    o1.x = acc[4]; o1.y = acc[5]; o1.z = acc[6]; o1.w = acc[7];
    out[(size_t)node * 32 + fl * 2]     = o0;
    out[(size_t)node * 32 + fl * 2 + 1] = o1;
}

extern "C" void kernel_launch(void* const* d_in, const int* in_sizes, int n_in,
                              void* d_out, int out_size, void* d_ws, size_t ws_size,
                              hipStream_t stream) {
    const float* x  = (const float*)d_in[0];
    const int*   ei = (const int*)d_in[1];
    const float* W1 = (const float*)d_in[2];
    const float* b1 = (const float*)d_in[3];
    const float* W2 = (const float*)d_in[4];
    const float* b2 = (const float*)d_in[5];

    int N = in_sizes[0] / D;       // 50000 (pack requires N <= 65536)
    int E = in_sizes[1] / 2;       // 600000
    const int* src = ei;
    const int* dst = ei + E;

    int nbuk = (N + 255) / 256;    // 196 buckets

    char* ws = (char*)d_ws;
    int*      bcnt   = (int*)(ws + 0);                    // nbuk*8 ctrs, line-padded (100 KB)
    unsigned* bucket = (unsigned*)(ws + 102400);          // nbuk*8*BCAP*4 = 12.85 MB
    int*      row_ptr= (int*)(ws + 12947456);             // N+1 ints
    float*    dinv   = (float*)(ws + 13147520);           // N floats
    int*      esrcs  = (int*)(ws + 13347520);             // E ints (sorted by dst)
    unsigned short* whi1 = (unsigned short*)(ws + 15747584);
    unsigned short* wlo1 = (unsigned short*)(ws + 15780352);
    unsigned short* whi2 = (unsigned short*)(ws + 15813120);
    unsigned short* wlo2 = (unsigned short*)(ws + 15845888);
    unsigned short* hfeat = (unsigned short*)(ws + 15878656); // N*D bf16 (12.8 MB)
    unsigned short* hmid  = (unsigned short*)(ws + 28678656); // N*D bf16 (12.8 MB)

    int eb4  = (E / 4 + 255) / 256;   // 4-edge-per-thread blocks (586)
    int gb   = (N + 63) / 64;         // gemm blocks (782)
    int ab16 = (N + 15) / 16;         // agg blocks (16 nodes/block)

    hipMemsetAsync(bcnt, 0, (size_t)nbuk * 8 * CPAD * sizeof(int), stream);
    bucket_wconv_kernel<<<eb4 + 128, 256, 0, stream>>>(src, dst, bcnt, bucket, E,
                                                       W1, W2, whi1, wlo1, whi2, wlo2, eb4);

    // CSR build + layer-1 GEMM fused (independent chains)
    build_gemm_kernel<<<nbuk + gb, 256, 0, stream>>>(bucket, bcnt, row_ptr, dinv, esrcs,
                                                     N, E, x, whi1, wlo1, hfeat, N, nbuk);

    // layer 1 agg + b1 + relu -> hmid (bf16)
    agg_bf16out_kernel<<<ab16, 256, 0, stream>>>(hfeat, dinv, row_ptr, esrcs, b1,
                                                 (uint4*)hmid, N);

    // layer 2: h2 = hmid @ W2 ; agg + b2 -> d_out (fp32)
    gemm_bf16a_kernel<<<gb, 256, 0, stream>>>(hmid, whi2, wlo2, hfeat, N);
    agg_f32out_kernel<<<ab16, 256, 0, stream>>>(hfeat, dinv, row_ptr, esrcs, b2,
                                                (float4*)d_out, N);
}